// Round 1
// baseline (1985.300 us; speedup 1.0000x reference)
//
#include <hip/hip_runtime.h>
#include <hip/hip_bf16.h>

typedef __attribute__((ext_vector_type(8))) short bf16x8;
typedef __attribute__((ext_vector_type(4))) float f32x4;

__device__ __forceinline__ unsigned short f2bf(float x) {
  union { float f; unsigned u; } v; v.f = x;
  unsigned r = v.u + 0x7fffu + ((v.u >> 16) & 1u);
  return (unsigned short)(r >> 16);
}
__device__ __forceinline__ float bflo(unsigned u) { union { unsigned v; float f; } x; x.v = u << 16; return x.f; }
__device__ __forceinline__ float bfhi(unsigned u) { union { unsigned v; float f; } x; x.v = u & 0xffff0000u; return x.f; }

// ---------------------------------------------------------------------------
// Projection GEMM: out[b,h,t,d] = (X[m,:] . W[n,:] + bias[n]) * scale
// X: [8192][1024] fp32, W: [1024][1024] fp32 (torch Linear => x @ W.T)
// out: bf16 in [B=4,H=16,T=2048,D=64] layout. scale=0.125 for Q else 1.
// 128x128 tile, BK=32, 4 waves (2x2), each wave 64x64 via 4x4 mfma 16x16x32.
// ---------------------------------------------------------------------------
__global__ __launch_bounds__(256) void proj_gemm(
    const float* __restrict__ A, const float* __restrict__ W,
    const float* __restrict__ bias, unsigned short* __restrict__ out,
    float scale) {
  const int K = 1024;
  __shared__ __align__(16) unsigned short As[2][128][40];
  __shared__ __align__(16) unsigned short Bs[2][128][40];
  const int tid = threadIdx.x;
  const int row0 = blockIdx.x * 128;
  const int col0 = blockIdx.y * 128;
  const int lane = tid & 63;
  const int wave = tid >> 6;
  const int wm = (wave >> 1) * 64, wn = (wave & 1) * 64;
  const int fr = lane & 15;
  const int fk = (lane >> 4) * 8;

  f32x4 acc[4][4] = {};

  auto stage = [&](int buf, int kt) {
    const int k0 = kt * 32;
#pragma unroll
    for (int c = 0; c < 4; ++c) {
      int f = c * 256 + tid;
      int r = f >> 3;
      int cc = (f & 7) << 2;
      const float4 a = *(const float4*)(&A[(size_t)(row0 + r) * K + k0 + cc]);
      ushort4 ha;
      ha.x = f2bf(a.x); ha.y = f2bf(a.y); ha.z = f2bf(a.z); ha.w = f2bf(a.w);
      *(ushort4*)(&As[buf][r][cc]) = ha;
      const float4 b = *(const float4*)(&W[(size_t)(col0 + r) * K + k0 + cc]);
      ushort4 hb;
      hb.x = f2bf(b.x); hb.y = f2bf(b.y); hb.z = f2bf(b.z); hb.w = f2bf(b.w);
      *(ushort4*)(&Bs[buf][r][cc]) = hb;
    }
  };

  stage(0, 0);
  __syncthreads();
  const int NK = K / 32;
  for (int kt = 0; kt < NK; ++kt) {
    const int buf = kt & 1;
    if (kt + 1 < NK) stage(buf ^ 1, kt + 1);
    bf16x8 af[4], bfv[4];
#pragma unroll
    for (int i = 0; i < 4; ++i) {
      af[i] = *(const bf16x8*)(&As[buf][wm + i * 16 + fr][fk]);
      bfv[i] = *(const bf16x8*)(&Bs[buf][wn + i * 16 + fr][fk]);
    }
#pragma unroll
    for (int i = 0; i < 4; ++i)
#pragma unroll
      for (int j = 0; j < 4; ++j)
        acc[i][j] = __builtin_amdgcn_mfma_f32_16x16x32_bf16(af[i], bfv[j], acc[i][j], 0, 0, 0);
    __syncthreads();
  }

#pragma unroll
  for (int j = 0; j < 4; ++j) {
    const int n = col0 + wn + j * 16 + fr;
    const float bv = bias[n];
    const int h = n >> 6, d = n & 63;
#pragma unroll
    for (int i = 0; i < 4; ++i) {
      const int mrow = row0 + wm + i * 16 + (lane >> 4) * 4;
#pragma unroll
      for (int r = 0; r < 4; ++r) {
        const int m = mrow + r;
        const int b = m >> 11, t = m & 2047;
        const float val = (acc[i][j][r] + bv) * scale;
        out[(((size_t)b * 16 + h) * 2048 + t) * 64 + d] = f2bf(val);
      }
    }
  }
}

// ---------------------------------------------------------------------------
// Output projection: out[m,n] = O[m,:] . Wo[n,:] + bo[n], fp32 out
// ---------------------------------------------------------------------------
__global__ __launch_bounds__(256) void out_gemm(
    const unsigned short* __restrict__ A, const float* __restrict__ W,
    const float* __restrict__ bias, float* __restrict__ out) {
  const int K = 1024;
  __shared__ __align__(16) unsigned short As[2][128][40];
  __shared__ __align__(16) unsigned short Bs[2][128][40];
  const int tid = threadIdx.x;
  const int row0 = blockIdx.x * 128;
  const int col0 = blockIdx.y * 128;
  const int lane = tid & 63;
  const int wave = tid >> 6;
  const int wm = (wave >> 1) * 64, wn = (wave & 1) * 64;
  const int fr = lane & 15;
  const int fk = (lane >> 4) * 8;

  f32x4 acc[4][4] = {};

  auto stage = [&](int buf, int kt) {
    const int k0 = kt * 32;
#pragma unroll
    for (int c = 0; c < 2; ++c) {
      int f = c * 256 + tid;
      int r = f >> 2;
      int cc = (f & 3) << 3;
      uint4 ra = *(const uint4*)(&A[(size_t)(row0 + r) * K + k0 + cc]);
      *(uint4*)(&As[buf][r][cc]) = ra;
    }
#pragma unroll
    for (int c = 0; c < 4; ++c) {
      int f = c * 256 + tid;
      int r = f >> 3;
      int cc = (f & 7) << 2;
      const float4 b = *(const float4*)(&W[(size_t)(col0 + r) * K + k0 + cc]);
      ushort4 hb;
      hb.x = f2bf(b.x); hb.y = f2bf(b.y); hb.z = f2bf(b.z); hb.w = f2bf(b.w);
      *(ushort4*)(&Bs[buf][r][cc]) = hb;
    }
  };

  stage(0, 0);
  __syncthreads();
  const int NK = K / 32;
  for (int kt = 0; kt < NK; ++kt) {
    const int buf = kt & 1;
    if (kt + 1 < NK) stage(buf ^ 1, kt + 1);
    bf16x8 af[4], bfv[4];
#pragma unroll
    for (int i = 0; i < 4; ++i) {
      af[i] = *(const bf16x8*)(&As[buf][wm + i * 16 + fr][fk]);
      bfv[i] = *(const bf16x8*)(&Bs[buf][wn + i * 16 + fr][fk]);
    }
#pragma unroll
    for (int i = 0; i < 4; ++i)
#pragma unroll
      for (int j = 0; j < 4; ++j)
        acc[i][j] = __builtin_amdgcn_mfma_f32_16x16x32_bf16(af[i], bfv[j], acc[i][j], 0, 0, 0);
    __syncthreads();
  }

#pragma unroll
  for (int j = 0; j < 4; ++j) {
    const int n = col0 + wn + j * 16 + fr;
    const float bv = bias[n];
#pragma unroll
    for (int i = 0; i < 4; ++i) {
      const int mrow = row0 + wm + i * 16 + (lane >> 4) * 4;
#pragma unroll
      for (int r = 0; r < 4; ++r) {
        const int m = mrow + r;
        out[(size_t)m * 1024 + n] = acc[i][j][r] + bv;
      }
    }
  }
}

// ---------------------------------------------------------------------------
// Causal flash attention, fp32 vector path.
// One thread owns one q row (q,O in registers). K/V tiles (64x64) staged
// to LDS as fp32. Online softmax over 16-wide chunks.
// qh is pre-scaled by 0.125. Output O: bf16 [B,T,C] (t-major for out proj).
// ---------------------------------------------------------------------------
__global__ __launch_bounds__(256) void attn_kernel(
    const unsigned short* __restrict__ qh, const unsigned short* __restrict__ kh,
    const unsigned short* __restrict__ vh, unsigned short* __restrict__ O) {
  __shared__ __align__(16) float Ks[64][68];
  __shared__ __align__(16) float Vs[64][68];
  const int tid = threadIdx.x;
  const int bh = blockIdx.y;  // b*16 + h
  const int qt = blockIdx.x;  // 0..7
  const int qi = qt * 256 + tid;
  const int b = bh >> 4, h = bh & 15;

  float qv[64];
  {
    const unsigned short* qp = qh + ((size_t)bh * 2048 + qi) * 64;
#pragma unroll
    for (int c = 0; c < 8; ++c) {
      const uint4 r4 = *(const uint4*)(qp + c * 8);
      qv[c * 8 + 0] = bflo(r4.x); qv[c * 8 + 1] = bfhi(r4.x);
      qv[c * 8 + 2] = bflo(r4.y); qv[c * 8 + 3] = bfhi(r4.y);
      qv[c * 8 + 4] = bflo(r4.z); qv[c * 8 + 5] = bfhi(r4.z);
      qv[c * 8 + 6] = bflo(r4.w); qv[c * 8 + 7] = bfhi(r4.w);
    }
  }

  float o[64];
#pragma unroll
  for (int d = 0; d < 64; ++d) o[d] = 0.f;
  float m = -INFINITY, l = 0.f;

  const int ntiles = qt * 4 + 4;
  const int sr = tid >> 2;
  const int sc = (tid & 3) << 4;

  for (int tile = 0; tile < ntiles; ++tile) {
    const int kv0 = tile * 64;
    {
      const unsigned short* kp = kh + ((size_t)bh * 2048 + kv0 + sr) * 64 + sc;
      const unsigned short* vp = vh + ((size_t)bh * 2048 + kv0 + sr) * 64 + sc;
      uint4 ra = *(const uint4*)kp;
      uint4 rb = *(const uint4*)(kp + 8);
      *(float4*)&Ks[sr][sc + 0] = make_float4(bflo(ra.x), bfhi(ra.x), bflo(ra.y), bfhi(ra.y));
      *(float4*)&Ks[sr][sc + 4] = make_float4(bflo(ra.z), bfhi(ra.z), bflo(ra.w), bfhi(ra.w));
      *(float4*)&Ks[sr][sc + 8] = make_float4(bflo(rb.x), bfhi(rb.x), bflo(rb.y), bfhi(rb.y));
      *(float4*)&Ks[sr][sc + 12] = make_float4(bflo(rb.z), bfhi(rb.z), bflo(rb.w), bfhi(rb.w));
      ra = *(const uint4*)vp;
      rb = *(const uint4*)(vp + 8);
      *(float4*)&Vs[sr][sc + 0] = make_float4(bflo(ra.x), bfhi(ra.x), bflo(ra.y), bfhi(ra.y));
      *(float4*)&Vs[sr][sc + 4] = make_float4(bflo(ra.z), bfhi(ra.z), bflo(ra.w), bfhi(ra.w));
      *(float4*)&Vs[sr][sc + 8] = make_float4(bflo(rb.x), bfhi(rb.x), bflo(rb.y), bfhi(rb.y));
      *(float4*)&Vs[sr][sc + 12] = make_float4(bflo(rb.z), bfhi(rb.z), bflo(rb.w), bfhi(rb.w));
    }
    __syncthreads();

    if (kv0 <= qi) {
      const int jmax = min(64, qi - kv0 + 1);
      for (int c0 = 0; c0 < 64 && c0 < jmax; c0 += 16) {
        float s[16];
        float mx = -INFINITY;
#pragma unroll
        for (int jj = 0; jj < 16; ++jj) {
          const int j = c0 + jj;
          float a = 0.f;
#pragma unroll
          for (int d = 0; d < 64; d += 4) {
            const float4 kk = *(const float4*)&Ks[j][d];
            a += qv[d] * kk.x; a += qv[d + 1] * kk.y;
            a += qv[d + 2] * kk.z; a += qv[d + 3] * kk.w;
          }
          s[jj] = (j < jmax) ? a : -INFINITY;
          mx = fmaxf(mx, s[jj]);
        }
        if (mx > m) {
          const float al = __expf(m - mx);
          m = mx;
          l *= al;
#pragma unroll
          for (int d = 0; d < 64; ++d) o[d] *= al;
        }
#pragma unroll
        for (int jj = 0; jj < 16; ++jj) {
          const float p = __expf(s[jj] - m);
          l += p;
#pragma unroll
          for (int d = 0; d < 64; d += 4) {
            const float4 vv = *(const float4*)&Vs[c0 + jj][d];
            o[d] += p * vv.x; o[d + 1] += p * vv.y;
            o[d + 2] += p * vv.z; o[d + 3] += p * vv.w;
          }
        }
      }
    }
    __syncthreads();
  }

  const float inv = 1.0f / l;
  unsigned short* op = O + ((size_t)b * 2048 + qi) * 1024 + h * 64;
#pragma unroll
  for (int d = 0; d < 64; d += 2) {
    const unsigned u = ((unsigned)f2bf(o[d + 1] * inv) << 16) | f2bf(o[d] * inv);
    *(unsigned*)(op + d) = u;
  }
}

extern "C" void kernel_launch(void* const* d_in, const int* in_sizes, int n_in,
                              void* d_out, int out_size, void* d_ws, size_t ws_size,
                              hipStream_t stream) {
  (void)in_sizes; (void)n_in; (void)out_size; (void)ws_size;
  const float* q = (const float*)d_in[0];
  const float* k = (const float*)d_in[1];
  const float* v = (const float*)d_in[2];
  const float* Wq = (const float*)d_in[3];
  const float* bq = (const float*)d_in[4];
  const float* Wk = (const float*)d_in[5];
  const float* bk = (const float*)d_in[6];
  const float* Wv = (const float*)d_in[7];
  const float* bv = (const float*)d_in[8];
  const float* Wo = (const float*)d_in[9];
  const float* bo = (const float*)d_in[10];
  float* out = (float*)d_out;

  const size_t SZ = (size_t)4 * 16 * 2048 * 64;  // 8,388,608 elements
  unsigned short* qh = (unsigned short*)d_ws;
  unsigned short* kh = qh + SZ;
  unsigned short* vh = kh + SZ;
  unsigned short* Ob = vh + SZ;  // attention output, [B,T,C] bf16

  dim3 g1(64, 8), b1(256);
  proj_gemm<<<g1, b1, 0, stream>>>(q, Wq, bq, qh, 0.125f);
  proj_gemm<<<g1, b1, 0, stream>>>(k, Wk, bk, kh, 1.0f);
  proj_gemm<<<g1, b1, 0, stream>>>(v, Wv, bv, vh, 1.0f);

  dim3 g2(8, 64), b2(256);
  attn_kernel<<<g2, b2, 0, stream>>>(qh, kh, vh, Ob);

  out_gemm<<<g1, b1, 0, stream>>>(Ob, Wo, bo, out);
}

// Round 2
// 334.686 us; speedup vs baseline: 5.9318x; 5.9318x over previous
//
#include <hip/hip_runtime.h>
#include <hip/hip_bf16.h>

typedef __attribute__((ext_vector_type(8))) short bf16x8;
typedef __attribute__((ext_vector_type(4))) float f32x4;

__device__ __forceinline__ unsigned short f2bf(float x) {
  union { float f; unsigned u; } v; v.f = x;
  unsigned r = v.u + 0x7fffu + ((v.u >> 16) & 1u);
  return (unsigned short)(r >> 16);
}

// XOR swizzle for 128-byte-row LDS tiles: flip bits 4-6 by (row&7)
#define SWZ(x) ((x) ^ ((((x) >> 7) & 7) << 4))

// ---------------------------------------------------------------------------
// Projection GEMM: out[...] = (X[m,:] . W[n,:] + bias[n]) * scale, bf16 out
// vtrans=0: out[b][h][t][d]  (Q, K);  vtrans=1: out[b][h][d][t]  (V)
// ---------------------------------------------------------------------------
__global__ __launch_bounds__(256) void proj_gemm(
    const float* __restrict__ A, const float* __restrict__ W,
    const float* __restrict__ bias, unsigned short* __restrict__ out,
    float scale, int vtrans) {
  const int K = 1024;
  __shared__ __align__(16) unsigned short As[2][128][40];
  __shared__ __align__(16) unsigned short Bs[2][128][40];
  const int tid = threadIdx.x;
  const int row0 = blockIdx.x * 128;
  const int col0 = blockIdx.y * 128;
  const int lane = tid & 63;
  const int wave = tid >> 6;
  const int wm = (wave >> 1) * 64, wn = (wave & 1) * 64;
  const int fr = lane & 15;
  const int fk = (lane >> 4) * 8;

  f32x4 acc[4][4] = {};

  auto stage = [&](int buf, int kt) {
    const int k0 = kt * 32;
#pragma unroll
    for (int c = 0; c < 4; ++c) {
      int f = c * 256 + tid;
      int r = f >> 3;
      int cc = (f & 7) << 2;
      const float4 a = *(const float4*)(&A[(size_t)(row0 + r) * K + k0 + cc]);
      ushort4 ha;
      ha.x = f2bf(a.x); ha.y = f2bf(a.y); ha.z = f2bf(a.z); ha.w = f2bf(a.w);
      *(ushort4*)(&As[buf][r][cc]) = ha;
      const float4 b = *(const float4*)(&W[(size_t)(col0 + r) * K + k0 + cc]);
      ushort4 hb;
      hb.x = f2bf(b.x); hb.y = f2bf(b.y); hb.z = f2bf(b.z); hb.w = f2bf(b.w);
      *(ushort4*)(&Bs[buf][r][cc]) = hb;
    }
  };

  stage(0, 0);
  __syncthreads();
  const int NK = K / 32;
  for (int kt = 0; kt < NK; ++kt) {
    const int buf = kt & 1;
    if (kt + 1 < NK) stage(buf ^ 1, kt + 1);
    bf16x8 af[4], bfv[4];
#pragma unroll
    for (int i = 0; i < 4; ++i) {
      af[i] = *(const bf16x8*)(&As[buf][wm + i * 16 + fr][fk]);
      bfv[i] = *(const bf16x8*)(&Bs[buf][wn + i * 16 + fr][fk]);
    }
#pragma unroll
    for (int i = 0; i < 4; ++i)
#pragma unroll
      for (int j = 0; j < 4; ++j)
        acc[i][j] = __builtin_amdgcn_mfma_f32_16x16x32_bf16(af[i], bfv[j], acc[i][j], 0, 0, 0);
    __syncthreads();
  }

#pragma unroll
  for (int j = 0; j < 4; ++j) {
    const int n = col0 + wn + j * 16 + fr;
    const float bv = bias[n];
    const int h = n >> 6, d = n & 63;
#pragma unroll
    for (int i = 0; i < 4; ++i) {
      const int mrow = row0 + wm + i * 16 + (lane >> 4) * 4;
#pragma unroll
      for (int r = 0; r < 4; ++r) {
        const int m = mrow + r;
        const int b = m >> 11, t = m & 2047;
        const float val = (acc[i][j][r] + bv) * scale;
        if (vtrans)
          out[(((size_t)b * 16 + h) * 64 + d) * 2048 + t] = f2bf(val);
        else
          out[(((size_t)b * 16 + h) * 2048 + t) * 64 + d] = f2bf(val);
      }
    }
  }
}

// ---------------------------------------------------------------------------
// Output projection: out[m,n] = O[m,:] . Wo[n,:] + bo[n], fp32 out
// ---------------------------------------------------------------------------
__global__ __launch_bounds__(256) void out_gemm(
    const unsigned short* __restrict__ A, const float* __restrict__ W,
    const float* __restrict__ bias, float* __restrict__ out) {
  const int K = 1024;
  __shared__ __align__(16) unsigned short As[2][128][40];
  __shared__ __align__(16) unsigned short Bs[2][128][40];
  const int tid = threadIdx.x;
  const int row0 = blockIdx.x * 128;
  const int col0 = blockIdx.y * 128;
  const int lane = tid & 63;
  const int wave = tid >> 6;
  const int wm = (wave >> 1) * 64, wn = (wave & 1) * 64;
  const int fr = lane & 15;
  const int fk = (lane >> 4) * 8;

  f32x4 acc[4][4] = {};

  auto stage = [&](int buf, int kt) {
    const int k0 = kt * 32;
#pragma unroll
    for (int c = 0; c < 2; ++c) {
      int f = c * 256 + tid;
      int r = f >> 2;
      int cc = (f & 3) << 3;
      uint4 ra = *(const uint4*)(&A[(size_t)(row0 + r) * K + k0 + cc]);
      *(uint4*)(&As[buf][r][cc]) = ra;
    }
#pragma unroll
    for (int c = 0; c < 4; ++c) {
      int f = c * 256 + tid;
      int r = f >> 3;
      int cc = (f & 7) << 2;
      const float4 b = *(const float4*)(&W[(size_t)(col0 + r) * K + k0 + cc]);
      ushort4 hb;
      hb.x = f2bf(b.x); hb.y = f2bf(b.y); hb.z = f2bf(b.z); hb.w = f2bf(b.w);
      *(ushort4*)(&Bs[buf][r][cc]) = hb;
    }
  };

  stage(0, 0);
  __syncthreads();
  const int NK = K / 32;
  for (int kt = 0; kt < NK; ++kt) {
    const int buf = kt & 1;
    if (kt + 1 < NK) stage(buf ^ 1, kt + 1);
    bf16x8 af[4], bfv[4];
#pragma unroll
    for (int i = 0; i < 4; ++i) {
      af[i] = *(const bf16x8*)(&As[buf][wm + i * 16 + fr][fk]);
      bfv[i] = *(const bf16x8*)(&Bs[buf][wn + i * 16 + fr][fk]);
    }
#pragma unroll
    for (int i = 0; i < 4; ++i)
#pragma unroll
      for (int j = 0; j < 4; ++j)
        acc[i][j] = __builtin_amdgcn_mfma_f32_16x16x32_bf16(af[i], bfv[j], acc[i][j], 0, 0, 0);
    __syncthreads();
  }

#pragma unroll
  for (int j = 0; j < 4; ++j) {
    const int n = col0 + wn + j * 16 + fr;
    const float bv = bias[n];
#pragma unroll
    for (int i = 0; i < 4; ++i) {
      const int mrow = row0 + wm + i * 16 + (lane >> 4) * 4;
#pragma unroll
      for (int r = 0; r < 4; ++r) {
        const int m = mrow + r;
        out[(size_t)m * 1024 + n] = acc[i][j][r] + bv;
      }
    }
  }
}

// ---------------------------------------------------------------------------
// MFMA causal flash attention.
// Block = 4 waves, 128 q-rows of one (b,h). Wave w owns rows qb=qt*128+w*32.
// S^T via mfma(K,Q): col=q (lane&15), row=kv -> softmax state lane-local.
// O^T via mfma(V^T, P^T): col=q -> rescale lane-local.
// K tile [64][64] bf16, V^T tile [64(d)][64(t)] bf16, both XOR-swizzled LDS.
// P^T through per-wave 4KB swizzled LDS buffer.
// qh pre-scaled by 0.125. Output Ob: bf16 [B][T][C].
// ---------------------------------------------------------------------------
__global__ __launch_bounds__(256) void attn_mfma(
    const unsigned short* __restrict__ qh, const unsigned short* __restrict__ kh,
    const unsigned short* __restrict__ vT, unsigned short* __restrict__ Ob) {
  __shared__ __align__(16) unsigned short Klds[64 * 64];
  __shared__ __align__(16) unsigned short Vlds[64 * 64];
  __shared__ __align__(16) unsigned short Plds[4][32 * 64];

  const int tid = threadIdx.x;
  const int lane = tid & 63;
  const int w = tid >> 6;
  const int bh = blockIdx.y;
  const int qt = (int)gridDim.x - 1 - (int)blockIdx.x;  // heavy blocks first
  const int qb = qt * 128 + w * 32;
  const int b = bh >> 4, h = bh & 15;
  const int q16 = lane & 15;
  const int g = lane >> 4;

  // Q fragments straight from global (row-major [bh][t][d], 16B aligned)
  bf16x8 qf[2][2];
  {
    const unsigned short* qp = qh + ((size_t)bh * 2048 + qb) * 64;
#pragma unroll
    for (int nq = 0; nq < 2; ++nq)
#pragma unroll
      for (int kk = 0; kk < 2; ++kk)
        qf[nq][kk] = *(const bf16x8*)(qp + (nq * 16 + q16) * 64 + kk * 32 + g * 8);
  }

  f32x4 acc_o[4][2] = {};  // [md (d chunk)][nq], O^T layout
  float m_run[2] = {-INFINITY, -INFINITY};
  float l_run[2] = {0.f, 0.f};

  const int nt = 2 * qt + 2;
  const int sr = tid >> 2;            // staging row 0..63
  const int scb = (tid & 3) * 32;     // byte col within 128B row

  for (int t = 0; t < nt; ++t) {
    const int kv0 = t * 64;
    __syncthreads();
    {
      const char* kp = (const char*)(kh + ((size_t)bh * 2048 + kv0 + sr) * 64);
      uint4 ra = *(const uint4*)(kp + scb);
      uint4 rb = *(const uint4*)(kp + scb + 16);
      *(uint4*)((char*)Klds + SWZ(sr * 128 + scb)) = ra;
      *(uint4*)((char*)Klds + SWZ(sr * 128 + scb + 16)) = rb;
      const char* vp = (const char*)(vT + ((size_t)bh * 64 + sr) * 2048 + kv0);
      uint4 rc = *(const uint4*)(vp + scb);
      uint4 rd = *(const uint4*)(vp + scb + 16);
      *(uint4*)((char*)Vlds + SWZ(sr * 128 + scb)) = rc;
      *(uint4*)((char*)Vlds + SWZ(sr * 128 + scb + 16)) = rd;
    }
    __syncthreads();

    if (kv0 >= qb + 32) continue;  // fully masked for this wave (wave-uniform)

    // ---- S^T = K @ Q^T : A=K rows, B=Q rows ----
    f32x4 sacc[4][2] = {};
#pragma unroll
    for (int kk = 0; kk < 2; ++kk) {
      bf16x8 kf[4];
#pragma unroll
      for (int mkv = 0; mkv < 4; ++mkv)
        kf[mkv] = *(const bf16x8*)((const char*)Klds +
                                   SWZ((mkv * 16 + q16) * 128 + kk * 64 + g * 16));
#pragma unroll
      for (int mkv = 0; mkv < 4; ++mkv)
#pragma unroll
        for (int nq = 0; nq < 2; ++nq)
          sacc[mkv][nq] = __builtin_amdgcn_mfma_f32_16x16x32_bf16(
              kf[mkv], qf[nq][kk], sacc[mkv][nq], 0, 0, 0);
    }

    // ---- online softmax (per lane: col q = q16, rows = kv) ----
    const bool diag = (kv0 + 64 > qb);
#pragma unroll
    for (int nq = 0; nq < 2; ++nq) {
      const int qa = qb + nq * 16 + q16;
      if (diag) {
#pragma unroll
        for (int mkv = 0; mkv < 4; ++mkv)
#pragma unroll
          for (int r = 0; r < 4; ++r) {
            const int kva = kv0 + mkv * 16 + g * 4 + r;
            if (kva > qa) sacc[mkv][nq][r] = -INFINITY;
          }
      }
      float mx = -INFINITY;
#pragma unroll
      for (int mkv = 0; mkv < 4; ++mkv) {
        mx = fmaxf(mx, fmaxf(fmaxf(sacc[mkv][nq][0], sacc[mkv][nq][1]),
                             fmaxf(sacc[mkv][nq][2], sacc[mkv][nq][3])));
      }
      mx = fmaxf(mx, __shfl_xor(mx, 16));
      mx = fmaxf(mx, __shfl_xor(mx, 32));
      const float mnew = fmaxf(m_run[nq], mx);
      const float al = __expf(m_run[nq] - mnew);
      m_run[nq] = mnew;
      float ls = 0.f;
#pragma unroll
      for (int mkv = 0; mkv < 4; ++mkv) {
        const float p0 = __expf(sacc[mkv][nq][0] - mnew);
        const float p1 = __expf(sacc[mkv][nq][1] - mnew);
        const float p2 = __expf(sacc[mkv][nq][2] - mnew);
        const float p3 = __expf(sacc[mkv][nq][3] - mnew);
        ls += (p0 + p1) + (p2 + p3);
        uint2 u;
        u.x = f2bf(p0) | ((unsigned)f2bf(p1) << 16);
        u.y = f2bf(p2) | ((unsigned)f2bf(p3) << 16);
        *(uint2*)((char*)Plds[w] +
                  SWZ((nq * 16 + q16) * 128 + mkv * 32 + g * 8)) = u;
      }
      ls += __shfl_xor(ls, 16);
      ls += __shfl_xor(ls, 32);
      l_run[nq] = l_run[nq] * al + ls;
#pragma unroll
      for (int md = 0; md < 4; ++md)
#pragma unroll
        for (int r = 0; r < 4; ++r) acc_o[md][nq][r] *= al;
    }
    // P_lds is per-wave: order write->read within the wave via waitcnt
    asm volatile("s_waitcnt lgkmcnt(0)" ::: "memory");

    // ---- O^T += V^T @ P : A=V^T rows (m=d), B=P^T rows (n=q) ----
#pragma unroll
    for (int kc = 0; kc < 2; ++kc) {
      bf16x8 vf[4], pf[2];
#pragma unroll
      for (int md = 0; md < 4; ++md)
        vf[md] = *(const bf16x8*)((const char*)Vlds +
                                  SWZ((md * 16 + q16) * 128 + kc * 64 + g * 16));
#pragma unroll
      for (int nq = 0; nq < 2; ++nq)
        pf[nq] = *(const bf16x8*)((const char*)Plds[w] +
                                  SWZ((nq * 16 + q16) * 128 + kc * 64 + g * 16));
#pragma unroll
      for (int md = 0; md < 4; ++md)
#pragma unroll
        for (int nq = 0; nq < 2; ++nq)
          acc_o[md][nq] = __builtin_amdgcn_mfma_f32_16x16x32_bf16(
              vf[md], pf[nq], acc_o[md][nq], 0, 0, 0);
    }
  }

  // ---- epilogue: O^T frag (row=d, col=q) -> Ob[b][t][h*64+d] ----
#pragma unroll
  for (int nq = 0; nq < 2; ++nq) {
    const float inv = 1.0f / l_run[nq];
    const int qa = qb + nq * 16 + q16;
    unsigned short* op = Ob + ((size_t)b * 2048 + qa) * 1024 + h * 64;
#pragma unroll
    for (int md = 0; md < 4; ++md) {
      const int d0 = md * 16 + g * 4;
      uint2 u;
      u.x = f2bf(acc_o[md][nq][0] * inv) |
            ((unsigned)f2bf(acc_o[md][nq][1] * inv) << 16);
      u.y = f2bf(acc_o[md][nq][2] * inv) |
            ((unsigned)f2bf(acc_o[md][nq][3] * inv) << 16);
      *(uint2*)(op + d0) = u;
    }
  }
}

extern "C" void kernel_launch(void* const* d_in, const int* in_sizes, int n_in,
                              void* d_out, int out_size, void* d_ws, size_t ws_size,
                              hipStream_t stream) {
  (void)in_sizes; (void)n_in; (void)out_size; (void)ws_size;
  const float* q = (const float*)d_in[0];
  const float* k = (const float*)d_in[1];
  const float* v = (const float*)d_in[2];
  const float* Wq = (const float*)d_in[3];
  const float* bq = (const float*)d_in[4];
  const float* Wk = (const float*)d_in[5];
  const float* bk = (const float*)d_in[6];
  const float* Wv = (const float*)d_in[7];
  const float* bv = (const float*)d_in[8];
  const float* Wo = (const float*)d_in[9];
  const float* bo = (const float*)d_in[10];
  float* out = (float*)d_out;

  const size_t SZ = (size_t)4 * 16 * 2048 * 64;  // 8,388,608 elements
  unsigned short* qh = (unsigned short*)d_ws;
  unsigned short* kh = qh + SZ;
  unsigned short* vT = kh + SZ;   // V transposed: [bh][d][t]
  unsigned short* Ob = vT + SZ;   // attention output, [B][T][C] bf16

  dim3 g1(64, 8), b1(256);
  proj_gemm<<<g1, b1, 0, stream>>>(q, Wq, bq, qh, 0.125f, 0);
  proj_gemm<<<g1, b1, 0, stream>>>(k, Wk, bk, kh, 1.0f, 0);
  proj_gemm<<<g1, b1, 0, stream>>>(v, Wv, bv, vT, 1.0f, 1);

  dim3 g2(16, 64), b2(256);
  attn_mfma<<<g2, b2, 0, stream>>>(qh, kh, vT, Ob);

  out_gemm<<<g1, b1, 0, stream>>>(Ob, Wo, bo, out);
}

// Round 3
// 256.365 us; speedup vs baseline: 7.7440x; 1.3055x over previous
//
#include <hip/hip_runtime.h>
#include <hip/hip_bf16.h>

typedef __attribute__((ext_vector_type(8))) short bf16x8;
typedef __attribute__((ext_vector_type(4))) float f32x4;
typedef __attribute__((ext_vector_type(16))) float f32x16;

__device__ __forceinline__ unsigned short f2bf(float x) {
  union { float f; unsigned u; } v; v.f = x;
  unsigned r = v.u + 0x7fffu + ((v.u >> 16) & 1u);
  return (unsigned short)(r >> 16);
}

__device__ __forceinline__ unsigned cvtpk_bf16(float lo, float hi) {
  unsigned r;
  asm("v_cvt_pk_bf16_f32 %0, %1, %2" : "=v"(r) : "v"(lo), "v"(hi));
  return r;
}
// v_permlane32_swap_b32 a, b : a' = [a_lo, b_lo], b' = [a_hi, b_hi]
__device__ __forceinline__ void pl32swap(unsigned &a, unsigned &b) {
  asm volatile("v_permlane32_swap_b32 %0, %1" : "+v"(a), "+v"(b));
}

// XOR swizzle for 128-byte-row LDS tiles: flip bits 4-6 by (row&7)
#define SWZ(x) ((x) ^ ((((x) >> 7) & 7) << 4))

// ---------------------------------------------------------------------------
// Projection GEMM: out[...] = (X[m,:] . W[n,:] + bias[n]) * scale, bf16 out
// vtrans=0: out[b][h][t][d]  (Q, K);  vtrans=1: out[b][h][d][t]  (V)
// ---------------------------------------------------------------------------
__global__ __launch_bounds__(256) void proj_gemm(
    const float* __restrict__ A, const float* __restrict__ W,
    const float* __restrict__ bias, unsigned short* __restrict__ out,
    float scale, int vtrans) {
  const int K = 1024;
  __shared__ __align__(16) unsigned short As[2][128][40];
  __shared__ __align__(16) unsigned short Bs[2][128][40];
  const int tid = threadIdx.x;
  const int row0 = blockIdx.x * 128;
  const int col0 = blockIdx.y * 128;
  const int lane = tid & 63;
  const int wave = tid >> 6;
  const int wm = (wave >> 1) * 64, wn = (wave & 1) * 64;
  const int fr = lane & 15;
  const int fk = (lane >> 4) * 8;

  f32x4 acc[4][4] = {};

  auto stage = [&](int buf, int kt) {
    const int k0 = kt * 32;
#pragma unroll
    for (int c = 0; c < 4; ++c) {
      int f = c * 256 + tid;
      int r = f >> 3;
      int cc = (f & 7) << 2;
      const float4 a = *(const float4*)(&A[(size_t)(row0 + r) * K + k0 + cc]);
      ushort4 ha;
      ha.x = f2bf(a.x); ha.y = f2bf(a.y); ha.z = f2bf(a.z); ha.w = f2bf(a.w);
      *(ushort4*)(&As[buf][r][cc]) = ha;
      const float4 b = *(const float4*)(&W[(size_t)(col0 + r) * K + k0 + cc]);
      ushort4 hb;
      hb.x = f2bf(b.x); hb.y = f2bf(b.y); hb.z = f2bf(b.z); hb.w = f2bf(b.w);
      *(ushort4*)(&Bs[buf][r][cc]) = hb;
    }
  };

  stage(0, 0);
  __syncthreads();
  const int NK = K / 32;
  for (int kt = 0; kt < NK; ++kt) {
    const int buf = kt & 1;
    if (kt + 1 < NK) stage(buf ^ 1, kt + 1);
    bf16x8 af[4], bfv[4];
#pragma unroll
    for (int i = 0; i < 4; ++i) {
      af[i] = *(const bf16x8*)(&As[buf][wm + i * 16 + fr][fk]);
      bfv[i] = *(const bf16x8*)(&Bs[buf][wn + i * 16 + fr][fk]);
    }
#pragma unroll
    for (int i = 0; i < 4; ++i)
#pragma unroll
      for (int j = 0; j < 4; ++j)
        acc[i][j] = __builtin_amdgcn_mfma_f32_16x16x32_bf16(af[i], bfv[j], acc[i][j], 0, 0, 0);
    __syncthreads();
  }

#pragma unroll
  for (int j = 0; j < 4; ++j) {
    const int n = col0 + wn + j * 16 + fr;
    const float bv = bias[n];
    const int h = n >> 6, d = n & 63;
#pragma unroll
    for (int i = 0; i < 4; ++i) {
      const int mrow = row0 + wm + i * 16 + (lane >> 4) * 4;
#pragma unroll
      for (int r = 0; r < 4; ++r) {
        const int m = mrow + r;
        const int b = m >> 11, t = m & 2047;
        const float val = (acc[i][j][r] + bv) * scale;
        if (vtrans)
          out[(((size_t)b * 16 + h) * 64 + d) * 2048 + t] = f2bf(val);
        else
          out[(((size_t)b * 16 + h) * 2048 + t) * 64 + d] = f2bf(val);
      }
    }
  }
}

// ---------------------------------------------------------------------------
// Output projection: out[m,n] = O[m,:] . Wo[n,:] + bo[n], fp32 out
// ---------------------------------------------------------------------------
__global__ __launch_bounds__(256) void out_gemm(
    const unsigned short* __restrict__ A, const float* __restrict__ W,
    const float* __restrict__ bias, float* __restrict__ out) {
  const int K = 1024;
  __shared__ __align__(16) unsigned short As[2][128][40];
  __shared__ __align__(16) unsigned short Bs[2][128][40];
  const int tid = threadIdx.x;
  const int row0 = blockIdx.x * 128;
  const int col0 = blockIdx.y * 128;
  const int lane = tid & 63;
  const int wave = tid >> 6;
  const int wm = (wave >> 1) * 64, wn = (wave & 1) * 64;
  const int fr = lane & 15;
  const int fk = (lane >> 4) * 8;

  f32x4 acc[4][4] = {};

  auto stage = [&](int buf, int kt) {
    const int k0 = kt * 32;
#pragma unroll
    for (int c = 0; c < 2; ++c) {
      int f = c * 256 + tid;
      int r = f >> 2;
      int cc = (f & 3) << 3;
      uint4 ra = *(const uint4*)(&A[(size_t)(row0 + r) * K + k0 + cc]);
      *(uint4*)(&As[buf][r][cc]) = ra;
    }
#pragma unroll
    for (int c = 0; c < 4; ++c) {
      int f = c * 256 + tid;
      int r = f >> 3;
      int cc = (f & 7) << 2;
      const float4 b = *(const float4*)(&W[(size_t)(col0 + r) * K + k0 + cc]);
      ushort4 hb;
      hb.x = f2bf(b.x); hb.y = f2bf(b.y); hb.z = f2bf(b.z); hb.w = f2bf(b.w);
      *(ushort4*)(&Bs[buf][r][cc]) = hb;
    }
  };

  stage(0, 0);
  __syncthreads();
  const int NK = K / 32;
  for (int kt = 0; kt < NK; ++kt) {
    const int buf = kt & 1;
    if (kt + 1 < NK) stage(buf ^ 1, kt + 1);
    bf16x8 af[4], bfv[4];
#pragma unroll
    for (int i = 0; i < 4; ++i) {
      af[i] = *(const bf16x8*)(&As[buf][wm + i * 16 + fr][fk]);
      bfv[i] = *(const bf16x8*)(&Bs[buf][wn + i * 16 + fr][fk]);
    }
#pragma unroll
    for (int i = 0; i < 4; ++i)
#pragma unroll
      for (int j = 0; j < 4; ++j)
        acc[i][j] = __builtin_amdgcn_mfma_f32_16x16x32_bf16(af[i], bfv[j], acc[i][j], 0, 0, 0);
    __syncthreads();
  }

#pragma unroll
  for (int j = 0; j < 4; ++j) {
    const int n = col0 + wn + j * 16 + fr;
    const float bv = bias[n];
#pragma unroll
    for (int i = 0; i < 4; ++i) {
      const int mrow = row0 + wm + i * 16 + (lane >> 4) * 4;
#pragma unroll
      for (int r = 0; r < 4; ++r) {
        const int m = mrow + r;
        out[(size_t)m * 1024 + n] = acc[i][j][r] + bv;
      }
    }
  }
}

// ---------------------------------------------------------------------------
// MFMA causal flash attention, 32x32x16, in-register softmax/P-exchange.
// Block = 4 waves; processes TWO q-tiles of 128 rows: qt=15-x then qt=x
// (uniform 34 kv-tile iterations per block). Wave w owns 32 q rows.
// S^T = mfma(K,Q): C col = q (lane&31) -> softmax lane-local + 1 shfl.
// P -> bf16 via v_cvt_pk, PV B-frags via v_permlane32_swap (no LDS bounce).
// O^T = mfma(V^T, P^T). K/V double-buffered in swizzled LDS, async staged.
// qh pre-scaled by 0.125*log2(e); exp2 domain. Output Ob: bf16 [B][T][C].
// ---------------------------------------------------------------------------
__global__ __launch_bounds__(256) void attn_mfma(
    const unsigned short* __restrict__ qh, const unsigned short* __restrict__ kh,
    const unsigned short* __restrict__ vT, unsigned short* __restrict__ Ob) {
  __shared__ __align__(16) unsigned short Klds[2][64 * 64];
  __shared__ __align__(16) unsigned short Vlds[2][64 * 64];

  const int tid = threadIdx.x;
  const int lane = tid & 63;
  const int w = tid >> 6;
  const int bh = blockIdx.y;
  const int b = bh >> 4, h = bh & 15;
  const int q32 = lane & 31;
  const int hi = lane >> 5;
  const int sr = tid >> 2;          // staging row 0..63
  const int scb = (tid & 3) * 32;   // byte col in 128B row

  const unsigned short* kbase = kh + (size_t)bh * 2048 * 64;
  const unsigned short* vbase = vT + (size_t)bh * 64 * 2048;

  for (int pass = 0; pass < 2; ++pass) {
    const int qt = pass == 0 ? (15 - (int)blockIdx.x) : (int)blockIdx.x;
    const int qb = qt * 128 + w * 32;
    const int nt = 2 * qt + 2;

    // Q fragments from global: lane: row q32, d = kk*16 + hi*8 + [0,8)
    bf16x8 qf[4];
    {
      const unsigned short* qp = qh + ((size_t)bh * 2048 + qb + q32) * 64;
#pragma unroll
      for (int kk = 0; kk < 4; ++kk)
        qf[kk] = *(const bf16x8*)(qp + kk * 16 + hi * 8);
    }

    f32x16 acc_o[2] = {};
    float m_run = -INFINITY, l_run = 0.f;

    // stage tile 0
    uint4 kr0, kr1, vr0, vr1;
    {
      const char* kp = (const char*)(kbase + (size_t)sr * 64);
      kr0 = *(const uint4*)(kp + scb); kr1 = *(const uint4*)(kp + scb + 16);
      const char* vp = (const char*)(vbase + (size_t)sr * 2048);
      vr0 = *(const uint4*)(vp + scb); vr1 = *(const uint4*)(vp + scb + 16);
    }
    __syncthreads();  // prior pass done reading buffers
    *(uint4*)((char*)Klds[0] + SWZ(sr * 128 + scb)) = kr0;
    *(uint4*)((char*)Klds[0] + SWZ(sr * 128 + scb + 16)) = kr1;
    *(uint4*)((char*)Vlds[0] + SWZ(sr * 128 + scb)) = vr0;
    *(uint4*)((char*)Vlds[0] + SWZ(sr * 128 + scb + 16)) = vr1;

    int cur = 0;
    for (int t = 0; t < nt; ++t) {
      const int kv0 = t * 64;
      // issue next-tile loads (latency hides under barrier+compute)
      if (t + 1 < nt) {
        const char* kp = (const char*)(kbase + (size_t)((t + 1) * 64 + sr) * 64);
        kr0 = *(const uint4*)(kp + scb); kr1 = *(const uint4*)(kp + scb + 16);
        const char* vp = (const char*)(vbase + (size_t)sr * 2048 + (t + 1) * 64);
        vr0 = *(const uint4*)(vp + scb); vr1 = *(const uint4*)(vp + scb + 16);
      }
      __syncthreads();  // buf[cur] ready

      if (kv0 < qb + 32) {  // wave-uniform causal skip
        const char* Kb = (const char*)Klds[cur];
        const char* Vb = (const char*)Vlds[cur];

        // ---- S^T = K @ Q^T ----
        f32x16 sacc[2] = {};
#pragma unroll
        for (int kk = 0; kk < 4; ++kk) {
          bf16x8 kf0 = *(const bf16x8*)(Kb + SWZ((q32) * 128 + kk * 32 + hi * 16));
          bf16x8 kf1 = *(const bf16x8*)(Kb + SWZ((32 + q32) * 128 + kk * 32 + hi * 16));
          sacc[0] = __builtin_amdgcn_mfma_f32_32x32x16_bf16(kf0, qf[kk], sacc[0], 0, 0, 0);
          sacc[1] = __builtin_amdgcn_mfma_f32_32x32x16_bf16(kf1, qf[kk], sacc[1], 0, 0, 0);
        }

        // ---- causal mask on diagonal tiles ----
        // lane holds col q=qb+q32; rows kv = kv0+mkv*32+4*hi+(r&3)+8*(r>>2)
        if (kv0 + 64 > qb) {
          const int qa = qb + q32;
#pragma unroll
          for (int mkv = 0; mkv < 2; ++mkv)
#pragma unroll
            for (int r = 0; r < 16; ++r) {
              const int kva = kv0 + mkv * 32 + 4 * hi + (r & 3) + 8 * (r >> 2);
              if (kva > qa) sacc[mkv][r] = -INFINITY;
            }
        }

        // ---- online softmax (exp2 domain) ----
        float mx = -INFINITY;
#pragma unroll
        for (int mkv = 0; mkv < 2; ++mkv)
#pragma unroll
          for (int r = 0; r < 16; ++r) mx = fmaxf(mx, sacc[mkv][r]);
        mx = fmaxf(mx, __shfl_xor(mx, 32));
        const float mnew = fmaxf(m_run, mx);
        const float al = exp2f(m_run - mnew);
        m_run = mnew;

        float ls = 0.f;
        unsigned W[2][8];
#pragma unroll
        for (int mkv = 0; mkv < 2; ++mkv)
#pragma unroll
          for (int s = 0; s < 8; ++s) {
            const float p0 = exp2f(sacc[mkv][2 * s] - mnew);
            const float p1 = exp2f(sacc[mkv][2 * s + 1] - mnew);
            ls += p0 + p1;
            W[mkv][s] = cvtpk_bf16(p0, p1);
          }
        ls += __shfl_xor(ls, 32);
        l_run = l_run * al + ls;
        acc_o[0] = acc_o[0] * al;
        acc_o[1] = acc_o[1] * al;

        // ---- P^T B-frags via permlane32_swap (in place -> j0..j3 order) ----
#pragma unroll
        for (int mkv = 0; mkv < 2; ++mkv) {
          pl32swap(W[mkv][0], W[mkv][2]);
          pl32swap(W[mkv][1], W[mkv][3]);
          pl32swap(W[mkv][4], W[mkv][6]);
          pl32swap(W[mkv][5], W[mkv][7]);
        }

        // ---- O^T += V^T @ P ----
#pragma unroll
        for (int wg = 0; wg < 4; ++wg) {
          union { unsigned u[4]; bf16x8 v; } pk;
          pk.u[0] = W[wg >> 1][(wg & 1) * 4 + 0];
          pk.u[1] = W[wg >> 1][(wg & 1) * 4 + 1];
          pk.u[2] = W[wg >> 1][(wg & 1) * 4 + 2];
          pk.u[3] = W[wg >> 1][(wg & 1) * 4 + 3];
          bf16x8 vf0 = *(const bf16x8*)(Vb + SWZ((q32) * 128 + wg * 32 + hi * 16));
          bf16x8 vf1 = *(const bf16x8*)(Vb + SWZ((32 + q32) * 128 + wg * 32 + hi * 16));
          acc_o[0] = __builtin_amdgcn_mfma_f32_32x32x16_bf16(vf0, pk.v, acc_o[0], 0, 0, 0);
          acc_o[1] = __builtin_amdgcn_mfma_f32_32x32x16_bf16(vf1, pk.v, acc_o[1], 0, 0, 0);
        }
      }

      // write prefetched tile into the other buffer
      if (t + 1 < nt) {
        const int nxt = cur ^ 1;
        *(uint4*)((char*)Klds[nxt] + SWZ(sr * 128 + scb)) = kr0;
        *(uint4*)((char*)Klds[nxt] + SWZ(sr * 128 + scb + 16)) = kr1;
        *(uint4*)((char*)Vlds[nxt] + SWZ(sr * 128 + scb)) = vr0;
        *(uint4*)((char*)Vlds[nxt] + SWZ(sr * 128 + scb + 16)) = vr1;
      }
      cur ^= 1;
    }

    // ---- epilogue: O^T (row=d, col=q) -> Ob[b][qa][h*64+d] ----
    {
      const float inv = 1.0f / l_run;
      const int qa = qb + q32;
      unsigned short* op = Ob + ((size_t)b * 2048 + qa) * 1024 + h * 64;
#pragma unroll
      for (int md = 0; md < 2; ++md)
#pragma unroll
        for (int rr = 0; rr < 4; ++rr) {
          uint2 u;
          u.x = cvtpk_bf16(acc_o[md][rr * 4 + 0] * inv, acc_o[md][rr * 4 + 1] * inv);
          u.y = cvtpk_bf16(acc_o[md][rr * 4 + 2] * inv, acc_o[md][rr * 4 + 3] * inv);
          *(uint2*)(op + md * 32 + rr * 8 + hi * 4) = u;
        }
    }
  }
}

extern "C" void kernel_launch(void* const* d_in, const int* in_sizes, int n_in,
                              void* d_out, int out_size, void* d_ws, size_t ws_size,
                              hipStream_t stream) {
  (void)in_sizes; (void)n_in; (void)out_size; (void)ws_size;
  const float* q = (const float*)d_in[0];
  const float* k = (const float*)d_in[1];
  const float* v = (const float*)d_in[2];
  const float* Wq = (const float*)d_in[3];
  const float* bq = (const float*)d_in[4];
  const float* Wk = (const float*)d_in[5];
  const float* bk = (const float*)d_in[6];
  const float* Wv = (const float*)d_in[7];
  const float* bv = (const float*)d_in[8];
  const float* Wo = (const float*)d_in[9];
  const float* bo = (const float*)d_in[10];
  float* out = (float*)d_out;

  const size_t SZ = (size_t)4 * 16 * 2048 * 64;  // 8,388,608 elements
  unsigned short* qh = (unsigned short*)d_ws;
  unsigned short* kh = qh + SZ;
  unsigned short* vT = kh + SZ;   // V transposed: [bh][d][t]
  unsigned short* Ob = vT + SZ;   // attention output, [B][T][C] bf16

  dim3 g1(64, 8), b1(256);
  // Q pre-scaled by D^-0.5 * log2(e) so attention works in exp2 domain
  proj_gemm<<<g1, b1, 0, stream>>>(q, Wq, bq, qh, 0.125f * 1.44269504088896f, 0);
  proj_gemm<<<g1, b1, 0, stream>>>(k, Wk, bk, kh, 1.0f, 0);
  proj_gemm<<<g1, b1, 0, stream>>>(v, Wv, bv, vT, 1.0f, 1);

  dim3 g2(8, 64), b2(256);
  attn_mfma<<<g2, b2, 0, stream>>>(qh, kh, vT, Ob);

  out_gemm<<<g1, b1, 0, stream>>>(Ob, Wo, bo, out);
}

// Round 4
// 246.077 us; speedup vs baseline: 8.0678x; 1.0418x over previous
//
#include <hip/hip_runtime.h>
#include <hip/hip_bf16.h>

typedef __attribute__((ext_vector_type(8))) short bf16x8;
typedef __attribute__((ext_vector_type(4))) float f32x4;
typedef __attribute__((ext_vector_type(16))) float f32x16;

__device__ __forceinline__ unsigned short f2bf(float x) {
  union { float f; unsigned u; } v; v.f = x;
  unsigned r = v.u + 0x7fffu + ((v.u >> 16) & 1u);
  return (unsigned short)(r >> 16);
}

__device__ __forceinline__ unsigned cvtpk_bf16(float lo, float hi) {
  unsigned r;
  asm("v_cvt_pk_bf16_f32 %0, %1, %2" : "=v"(r) : "v"(lo), "v"(hi));
  return r;
}
// v_permlane32_swap_b32 a, b : a' = [a_lo, b_lo], b' = [a_hi, b_hi]
__device__ __forceinline__ void pl32swap(unsigned &a, unsigned &b) {
  asm volatile("v_permlane32_swap_b32 %0, %1" : "+v"(a), "+v"(b));
}

__device__ __forceinline__ void gload_lds16(const void* g, void* l) {
  __builtin_amdgcn_global_load_lds((const __attribute__((address_space(1))) void*)g,
                                   (__attribute__((address_space(3))) void*)l, 16, 0, 0);
}

// XOR swizzle for 128-byte-row LDS tiles: flip bits 4-6 by (row&7)
#define SWZ(x) ((x) ^ ((((x) >> 7) & 7) << 4))

// ---------------------------------------------------------------------------
// Merged Q/K/V projection GEMM: z = blockIdx.z selects (A, W, bias, out).
// out[...] = (X[m,:] . W[n,:] + bias[n]) * scale, bf16 out
// z=0 (Q): scale=0.125*log2e, layout [b][h][t][d]
// z=1 (K): layout [b][h][t][d];  z=2 (V): transposed [b][h][d][t]
// 128x128 tile, BK=32, 4 waves, mfma 16x16x32. Staging via v_cvt_pk_bf16_f32.
// ---------------------------------------------------------------------------
__global__ __launch_bounds__(256) void proj_gemm3(
    const float* __restrict__ A0, const float* __restrict__ A1, const float* __restrict__ A2,
    const float* __restrict__ W0, const float* __restrict__ W1, const float* __restrict__ W2,
    const float* __restrict__ b0, const float* __restrict__ b1, const float* __restrict__ b2,
    unsigned short* __restrict__ o0, unsigned short* __restrict__ o1, unsigned short* __restrict__ o2) {
  const int K = 1024;
  __shared__ __align__(16) unsigned short As[2][128][40];
  __shared__ __align__(16) unsigned short Bs[2][128][40];
  const int z = blockIdx.z;
  const float* A = (z == 0) ? A0 : (z == 1) ? A1 : A2;
  const float* W = (z == 0) ? W0 : (z == 1) ? W1 : W2;
  const float* bias = (z == 0) ? b0 : (z == 1) ? b1 : b2;
  unsigned short* out = (z == 0) ? o0 : (z == 1) ? o1 : o2;
  const float scale = (z == 0) ? 0.125f * 1.4426950408889634f : 1.0f;
  const int vtrans = (z == 2);

  const int tid = threadIdx.x;
  const int row0 = blockIdx.x * 128;
  const int col0 = blockIdx.y * 128;
  const int lane = tid & 63;
  const int wave = tid >> 6;
  const int wm = (wave >> 1) * 64, wn = (wave & 1) * 64;
  const int fr = lane & 15;
  const int fk = (lane >> 4) * 8;

  f32x4 acc[4][4] = {};

  const int srow = tid >> 1;
  const int sc0 = (tid & 1) << 4;

  auto stage = [&](int buf, int kt) {
    const int k0 = kt * 32;
    {
      const float4* ap = (const float4*)(&A[(size_t)(row0 + srow) * K + k0 + sc0]);
      float4 x0 = ap[0], x1 = ap[1], x2 = ap[2], x3 = ap[3];
      uint4 u, v;
      u.x = cvtpk_bf16(x0.x, x0.y); u.y = cvtpk_bf16(x0.z, x0.w);
      u.z = cvtpk_bf16(x1.x, x1.y); u.w = cvtpk_bf16(x1.z, x1.w);
      v.x = cvtpk_bf16(x2.x, x2.y); v.y = cvtpk_bf16(x2.z, x2.w);
      v.z = cvtpk_bf16(x3.x, x3.y); v.w = cvtpk_bf16(x3.z, x3.w);
      *(uint4*)(&As[buf][srow][sc0]) = u;
      *(uint4*)(&As[buf][srow][sc0 + 8]) = v;
    }
    {
      const float4* bp = (const float4*)(&W[(size_t)(col0 + srow) * K + k0 + sc0]);
      float4 x0 = bp[0], x1 = bp[1], x2 = bp[2], x3 = bp[3];
      uint4 u, v;
      u.x = cvtpk_bf16(x0.x, x0.y); u.y = cvtpk_bf16(x0.z, x0.w);
      u.z = cvtpk_bf16(x1.x, x1.y); u.w = cvtpk_bf16(x1.z, x1.w);
      v.x = cvtpk_bf16(x2.x, x2.y); v.y = cvtpk_bf16(x2.z, x2.w);
      v.z = cvtpk_bf16(x3.x, x3.y); v.w = cvtpk_bf16(x3.z, x3.w);
      *(uint4*)(&Bs[buf][srow][sc0]) = u;
      *(uint4*)(&Bs[buf][srow][sc0 + 8]) = v;
    }
  };

  stage(0, 0);
  __syncthreads();
  const int NK = K / 32;
  for (int kt = 0; kt < NK; ++kt) {
    const int buf = kt & 1;
    if (kt + 1 < NK) stage(buf ^ 1, kt + 1);
    bf16x8 af[4], bfv[4];
#pragma unroll
    for (int i = 0; i < 4; ++i) {
      af[i] = *(const bf16x8*)(&As[buf][wm + i * 16 + fr][fk]);
      bfv[i] = *(const bf16x8*)(&Bs[buf][wn + i * 16 + fr][fk]);
    }
#pragma unroll
    for (int i = 0; i < 4; ++i)
#pragma unroll
      for (int j = 0; j < 4; ++j)
        acc[i][j] = __builtin_amdgcn_mfma_f32_16x16x32_bf16(af[i], bfv[j], acc[i][j], 0, 0, 0);
    __syncthreads();
  }

#pragma unroll
  for (int j = 0; j < 4; ++j) {
    const int n = col0 + wn + j * 16 + fr;
    const float bv = bias[n];
    const int h = n >> 6, d = n & 63;
#pragma unroll
    for (int i = 0; i < 4; ++i) {
      const int mrow = row0 + wm + i * 16 + (lane >> 4) * 4;
#pragma unroll
      for (int r = 0; r < 4; ++r) {
        const int m = mrow + r;
        const int b = m >> 11, t = m & 2047;
        const float val = (acc[i][j][r] + bv) * scale;
        if (vtrans)
          out[(((size_t)b * 16 + h) * 64 + d) * 2048 + t] = f2bf(val);
        else
          out[(((size_t)b * 16 + h) * 2048 + t) * 64 + d] = f2bf(val);
      }
    }
  }
}

// ---------------------------------------------------------------------------
// Output projection: out[m,n] = O[m,:] . Wo[n,:] + bo[n], fp32 out
// ---------------------------------------------------------------------------
__global__ __launch_bounds__(256) void out_gemm(
    const unsigned short* __restrict__ A, const float* __restrict__ W,
    const float* __restrict__ bias, float* __restrict__ out) {
  const int K = 1024;
  __shared__ __align__(16) unsigned short As[2][128][40];
  __shared__ __align__(16) unsigned short Bs[2][128][40];
  const int tid = threadIdx.x;
  const int row0 = blockIdx.x * 128;
  const int col0 = blockIdx.y * 128;
  const int lane = tid & 63;
  const int wave = tid >> 6;
  const int wm = (wave >> 1) * 64, wn = (wave & 1) * 64;
  const int fr = lane & 15;
  const int fk = (lane >> 4) * 8;

  f32x4 acc[4][4] = {};

  const int srow = tid >> 1;
  const int sc0 = (tid & 1) << 4;

  auto stage = [&](int buf, int kt) {
    const int k0 = kt * 32;
    {
      // A already bf16: 16 elems = 32B = 2 uint4
      const uint4* ap = (const uint4*)(&A[(size_t)(row0 + srow) * K + k0 + sc0]);
      uint4 ra = ap[0], rb = ap[1];
      *(uint4*)(&As[buf][srow][sc0]) = ra;
      *(uint4*)(&As[buf][srow][sc0 + 8]) = rb;
    }
    {
      const float4* bp = (const float4*)(&W[(size_t)(col0 + srow) * K + k0 + sc0]);
      float4 x0 = bp[0], x1 = bp[1], x2 = bp[2], x3 = bp[3];
      uint4 u, v;
      u.x = cvtpk_bf16(x0.x, x0.y); u.y = cvtpk_bf16(x0.z, x0.w);
      u.z = cvtpk_bf16(x1.x, x1.y); u.w = cvtpk_bf16(x1.z, x1.w);
      v.x = cvtpk_bf16(x2.x, x2.y); v.y = cvtpk_bf16(x2.z, x2.w);
      v.z = cvtpk_bf16(x3.x, x3.y); v.w = cvtpk_bf16(x3.z, x3.w);
      *(uint4*)(&Bs[buf][srow][sc0]) = u;
      *(uint4*)(&Bs[buf][srow][sc0 + 8]) = v;
    }
  };

  stage(0, 0);
  __syncthreads();
  const int NK = K / 32;
  for (int kt = 0; kt < NK; ++kt) {
    const int buf = kt & 1;
    if (kt + 1 < NK) stage(buf ^ 1, kt + 1);
    bf16x8 af[4], bfv[4];
#pragma unroll
    for (int i = 0; i < 4; ++i) {
      af[i] = *(const bf16x8*)(&As[buf][wm + i * 16 + fr][fk]);
      bfv[i] = *(const bf16x8*)(&Bs[buf][wn + i * 16 + fr][fk]);
    }
#pragma unroll
    for (int i = 0; i < 4; ++i)
#pragma unroll
      for (int j = 0; j < 4; ++j)
        acc[i][j] = __builtin_amdgcn_mfma_f32_16x16x32_bf16(af[i], bfv[j], acc[i][j], 0, 0, 0);
    __syncthreads();
  }

#pragma unroll
  for (int j = 0; j < 4; ++j) {
    const int n = col0 + wn + j * 16 + fr;
    const float bv = bias[n];
#pragma unroll
    for (int i = 0; i < 4; ++i) {
      const int mrow = row0 + wm + i * 16 + (lane >> 4) * 4;
#pragma unroll
      for (int r = 0; r < 4; ++r) {
        const int m = mrow + r;
        out[(size_t)m * 1024 + n] = acc[i][j][r] + bv;
      }
    }
  }
}

// ---------------------------------------------------------------------------
// MFMA causal flash attention, 32x32x16, in-register softmax/P-exchange.
// K/V staged via global_load_lds (linear LDS dest, inverse-swizzled global
// source; reads use the same XOR involution). Double-buffered, one barrier
// per tile, loads issued before compute. Defer-max (THR=8, exp2 domain).
// Block = 4 waves; two q-tiles (15-x, x) for uniform 34 tiles/block.
// qh pre-scaled by 0.125*log2(e). Output Ob: bf16 [B][T][C].
// ---------------------------------------------------------------------------
__global__ __launch_bounds__(256) void attn_mfma(
    const unsigned short* __restrict__ qh, const unsigned short* __restrict__ kh,
    const unsigned short* __restrict__ vT, unsigned short* __restrict__ Ob) {
  __shared__ __align__(16) unsigned short Klds[2][64 * 64];
  __shared__ __align__(16) unsigned short Vlds[2][64 * 64];

  const int tid = threadIdx.x;
  const int lane = tid & 63;
  const int w = tid >> 6;
  const int bh = blockIdx.y;
  const int b = bh >> 4, h = bh & 15;
  const int q32 = lane & 31;
  const int hi = lane >> 5;

  const char* kbase = (const char*)(kh + (size_t)bh * 2048 * 64);
  const char* vbase = (const char*)(vT + (size_t)bh * 64 * 2048);

  // per-lane source column (inverse-swizzle): data for LDS slot lane*16 of
  // chunk c lives at global row r=c*8+(lane>>3), col ((lane&7)^(lane>>3))*16
  const int lrow = lane >> 3;
  const int cb = (((lane & 7) ^ lrow) << 4);

  auto stage = [&](int buf, int t) {
    const int kv0 = t * 64;
#pragma unroll
    for (int j = 0; j < 2; ++j) {
      const int c = w * 2 + j;
      const int r = c * 8 + lrow;
      gload_lds16(kbase + (size_t)(kv0 + r) * 128 + cb,
                  (char*)Klds[buf] + c * 1024);
      gload_lds16(vbase + (size_t)r * 4096 + (size_t)kv0 * 2 + cb,
                  (char*)Vlds[buf] + c * 1024);
    }
  };

  for (int pass = 0; pass < 2; ++pass) {
    const int qt = pass == 0 ? (15 - (int)blockIdx.x) : (int)blockIdx.x;
    const int qb = qt * 128 + w * 32;
    const int nt = 2 * qt + 2;

    // Q fragments from global: lane: row q32, d = kk*16 + hi*8 + [0,8)
    bf16x8 qf[4];
    {
      const unsigned short* qp = qh + ((size_t)bh * 2048 + qb + q32) * 64;
#pragma unroll
      for (int kk = 0; kk < 4; ++kk)
        qf[kk] = *(const bf16x8*)(qp + kk * 16 + hi * 8);
    }

    f32x16 acc_o[2] = {};
    float m_run = -INFINITY, l_run = 0.f;

    stage(0, 0);
    __syncthreads();  // drains vmcnt -> buf0 ready

    int cur = 0;
    for (int t = 0; t < nt; ++t) {
      const int kv0 = t * 64;
      if (t + 1 < nt) stage(cur ^ 1, t + 1);  // async, drained by barrier below

      if (kv0 < qb + 32) {  // wave-uniform causal skip
        const char* Kb = (const char*)Klds[cur];
        const char* Vb = (const char*)Vlds[cur];

        // ---- S^T = K @ Q^T ----
        f32x16 sacc[2] = {};
        __builtin_amdgcn_s_setprio(1);
#pragma unroll
        for (int kk = 0; kk < 4; ++kk) {
          bf16x8 kf0 = *(const bf16x8*)(Kb + SWZ((q32) * 128 + kk * 32 + hi * 16));
          bf16x8 kf1 = *(const bf16x8*)(Kb + SWZ((32 + q32) * 128 + kk * 32 + hi * 16));
          sacc[0] = __builtin_amdgcn_mfma_f32_32x32x16_bf16(kf0, qf[kk], sacc[0], 0, 0, 0);
          sacc[1] = __builtin_amdgcn_mfma_f32_32x32x16_bf16(kf1, qf[kk], sacc[1], 0, 0, 0);
        }
        __builtin_amdgcn_s_setprio(0);

        // ---- causal mask on diagonal tiles ----
        if (kv0 + 64 > qb) {
          const int qa = qb + q32;
#pragma unroll
          for (int mkv = 0; mkv < 2; ++mkv)
#pragma unroll
            for (int r = 0; r < 16; ++r) {
              const int kva = kv0 + mkv * 32 + 4 * hi + (r & 3) + 8 * (r >> 2);
              if (kva > qa) sacc[mkv][r] = -INFINITY;
            }
        }

        // ---- online softmax, defer-max (exp2 domain) ----
        float mx = -INFINITY;
#pragma unroll
        for (int mkv = 0; mkv < 2; ++mkv)
#pragma unroll
          for (int r = 0; r < 16; ++r) mx = fmaxf(mx, sacc[mkv][r]);
        mx = fmaxf(mx, __shfl_xor(mx, 32));
        if (!__all(mx <= m_run + 8.f)) {
          const float mnew = fmaxf(m_run, mx);
          const float al = exp2f(m_run - mnew);
          m_run = mnew;
          l_run *= al;
          acc_o[0] = acc_o[0] * al;
          acc_o[1] = acc_o[1] * al;
        }

        float ls = 0.f;
        unsigned W[2][8];
#pragma unroll
        for (int mkv = 0; mkv < 2; ++mkv)
#pragma unroll
          for (int s = 0; s < 8; ++s) {
            const float p0 = exp2f(sacc[mkv][2 * s] - m_run);
            const float p1 = exp2f(sacc[mkv][2 * s + 1] - m_run);
            ls += p0 + p1;
            W[mkv][s] = cvtpk_bf16(p0, p1);
          }
        ls += __shfl_xor(ls, 32);
        l_run += ls;

        // ---- P^T B-frags via permlane32_swap (in place -> j0..j3 order) ----
#pragma unroll
        for (int mkv = 0; mkv < 2; ++mkv) {
          pl32swap(W[mkv][0], W[mkv][2]);
          pl32swap(W[mkv][1], W[mkv][3]);
          pl32swap(W[mkv][4], W[mkv][6]);
          pl32swap(W[mkv][5], W[mkv][7]);
        }

        // ---- O^T += V^T @ P ----
        __builtin_amdgcn_s_setprio(1);
#pragma unroll
        for (int wg = 0; wg < 4; ++wg) {
          union { unsigned u[4]; bf16x8 v; } pk;
          pk.u[0] = W[wg >> 1][(wg & 1) * 4 + 0];
          pk.u[1] = W[wg >> 1][(wg & 1) * 4 + 1];
          pk.u[2] = W[wg >> 1][(wg & 1) * 4 + 2];
          pk.u[3] = W[wg >> 1][(wg & 1) * 4 + 3];
          bf16x8 vf0 = *(const bf16x8*)(Vb + SWZ((q32) * 128 + wg * 32 + hi * 16));
          bf16x8 vf1 = *(const bf16x8*)(Vb + SWZ((32 + q32) * 128 + wg * 32 + hi * 16));
          acc_o[0] = __builtin_amdgcn_mfma_f32_32x32x16_bf16(vf0, pk.v, acc_o[0], 0, 0, 0);
          acc_o[1] = __builtin_amdgcn_mfma_f32_32x32x16_bf16(vf1, pk.v, acc_o[1], 0, 0, 0);
        }
        __builtin_amdgcn_s_setprio(0);
      }

      __syncthreads();  // drains vmcnt(0): next buffer staged & all reads done
      cur ^= 1;
    }

    // ---- epilogue: O^T (row=d, col=q) -> Ob[b][qa][h*64+d] ----
    {
      const float inv = 1.0f / l_run;
      const int qa = qb + q32;
      unsigned short* op = Ob + ((size_t)b * 2048 + qa) * 1024 + h * 64;
#pragma unroll
      for (int md = 0; md < 2; ++md)
#pragma unroll
        for (int rr = 0; rr < 4; ++rr) {
          uint2 u;
          u.x = cvtpk_bf16(acc_o[md][rr * 4 + 0] * inv, acc_o[md][rr * 4 + 1] * inv);
          u.y = cvtpk_bf16(acc_o[md][rr * 4 + 2] * inv, acc_o[md][rr * 4 + 3] * inv);
          *(uint2*)(op + md * 32 + rr * 8 + hi * 4) = u;
        }
    }
  }
}

extern "C" void kernel_launch(void* const* d_in, const int* in_sizes, int n_in,
                              void* d_out, int out_size, void* d_ws, size_t ws_size,
                              hipStream_t stream) {
  (void)in_sizes; (void)n_in; (void)out_size; (void)ws_size;
  const float* q = (const float*)d_in[0];
  const float* k = (const float*)d_in[1];
  const float* v = (const float*)d_in[2];
  const float* Wq = (const float*)d_in[3];
  const float* bq = (const float*)d_in[4];
  const float* Wk = (const float*)d_in[5];
  const float* bk = (const float*)d_in[6];
  const float* Wv = (const float*)d_in[7];
  const float* bv = (const float*)d_in[8];
  const float* Wo = (const float*)d_in[9];
  const float* bo = (const float*)d_in[10];
  float* out = (float*)d_out;

  const size_t SZ = (size_t)4 * 16 * 2048 * 64;  // 8,388,608 elements
  unsigned short* qh = (unsigned short*)d_ws;
  unsigned short* kh = qh + SZ;
  unsigned short* vT = kh + SZ;   // V transposed: [bh][d][t]
  unsigned short* Ob = vT + SZ;   // attention output, [B][T][C] bf16

  dim3 g1(64, 8, 3), b1(256);
  proj_gemm3<<<g1, b1, 0, stream>>>(q, k, v, Wq, Wk, Wv, bq, bk, bv, qh, kh, vT);

  dim3 g2(8, 64), b2(256);
  attn_mfma<<<g2, b2, 0, stream>>>(qh, kh, vT, Ob);

  dim3 g3(64, 8), b3(256);
  out_gemm<<<g3, b3, 0, stream>>>(Ob, Wo, bo, out);
}

// Round 5
// 242.188 us; speedup vs baseline: 8.1974x; 1.0161x over previous
//
#include <hip/hip_runtime.h>
#include <hip/hip_bf16.h>

typedef __attribute__((ext_vector_type(8))) short bf16x8;
typedef __attribute__((ext_vector_type(4))) float f32x4;
typedef __attribute__((ext_vector_type(16))) float f32x16;

__device__ __forceinline__ unsigned short f2bf(float x) {
  union { float f; unsigned u; } v; v.f = x;
  unsigned r = v.u + 0x7fffu + ((v.u >> 16) & 1u);
  return (unsigned short)(r >> 16);
}

__device__ __forceinline__ unsigned cvtpk_bf16(float lo, float hi) {
  unsigned r;
  asm("v_cvt_pk_bf16_f32 %0, %1, %2" : "=v"(r) : "v"(lo), "v"(hi));
  return r;
}
// v_permlane32_swap_b32 a, b : a' = [a_lo, b_lo], b' = [a_hi, b_hi]
__device__ __forceinline__ void pl32swap(unsigned &a, unsigned &b) {
  asm volatile("v_permlane32_swap_b32 %0, %1" : "+v"(a), "+v"(b));
}

__device__ __forceinline__ void gload_lds16(const void* g, void* l) {
  __builtin_amdgcn_global_load_lds((const __attribute__((address_space(1))) void*)g,
                                   (__attribute__((address_space(3))) void*)l, 16, 0, 0);
}

// XOR swizzle for 128-byte-row LDS tiles: flip bits 4-6 by (row&7)
#define SWZ(x) ((x) ^ ((((x) >> 7) & 7) << 4))

// ---------------------------------------------------------------------------
// Merged Q/K/V projection GEMM: z = blockIdx.z selects (A, W, bias, out).
// out[...] = (X[m,:] . W[n,:] + bias[n]) * scale, bf16 out
// z=0 (Q): scale=0.125*log2e, layout [b][h][t][d]
// z=1 (K): layout [b][h][t][d];  z=2 (V): transposed [b][h][d][t]
// 128x128 tile, BK=32, 4 waves, mfma 16x16x32.
// Staging: 8 threads/row (conflict-free b64 writes), cvt_pk, T14 split
// (global loads issued before MFMA, cvt+LDS-write after).
// ---------------------------------------------------------------------------
__global__ __launch_bounds__(256) void proj_gemm3(
    const float* __restrict__ A0, const float* __restrict__ A1, const float* __restrict__ A2,
    const float* __restrict__ W0, const float* __restrict__ W1, const float* __restrict__ W2,
    const float* __restrict__ b0, const float* __restrict__ b1, const float* __restrict__ b2,
    unsigned short* __restrict__ o0, unsigned short* __restrict__ o1, unsigned short* __restrict__ o2) {
  const int K = 1024;
  __shared__ __align__(16) unsigned short As[2][128][40];
  __shared__ __align__(16) unsigned short Bs[2][128][40];
  const int z = blockIdx.z;
  const float* A = (z == 0) ? A0 : (z == 1) ? A1 : A2;
  const float* W = (z == 0) ? W0 : (z == 1) ? W1 : W2;
  const float* bias = (z == 0) ? b0 : (z == 1) ? b1 : b2;
  unsigned short* out = (z == 0) ? o0 : (z == 1) ? o1 : o2;
  const float scale = (z == 0) ? 0.125f * 1.4426950408889634f : 1.0f;
  const int vtrans = (z == 2);

  const int tid = threadIdx.x;
  const int row0 = blockIdx.x * 128;
  const int col0 = blockIdx.y * 128;
  const int lane = tid & 63;
  const int wave = tid >> 6;
  const int wm = (wave >> 1) * 64, wn = (wave & 1) * 64;
  const int fr = lane & 15;
  const int fk = (lane >> 4) * 8;

  f32x4 acc[4][4] = {};

  // staging: chunk c covers rows c*32 + (tid>>3), col (tid&7)*4 floats
  const int sr = tid >> 3;
  const int sc = (tid & 7) * 4;
  const float* Ap[4];
  const float* Wp[4];
#pragma unroll
  for (int c = 0; c < 4; ++c) {
    Ap[c] = &A[(size_t)(row0 + c * 32 + sr) * K + sc];
    Wp[c] = &W[(size_t)(col0 + c * 32 + sr) * K + sc];
  }

  float4 la[4], lb[4];
  auto load = [&](int kt) {
    const int k0 = kt * 32;
#pragma unroll
    for (int c = 0; c < 4; ++c) {
      la[c] = *(const float4*)(Ap[c] + k0);
      lb[c] = *(const float4*)(Wp[c] + k0);
    }
  };
  auto store = [&](int buf) {
#pragma unroll
    for (int c = 0; c < 4; ++c) {
      uint2 ua, ub;
      ua.x = cvtpk_bf16(la[c].x, la[c].y); ua.y = cvtpk_bf16(la[c].z, la[c].w);
      ub.x = cvtpk_bf16(lb[c].x, lb[c].y); ub.y = cvtpk_bf16(lb[c].z, lb[c].w);
      *(uint2*)(&As[buf][c * 32 + sr][sc]) = ua;
      *(uint2*)(&Bs[buf][c * 32 + sr][sc]) = ub;
    }
  };

  load(0);
  store(0);
  __syncthreads();
  const int NK = K / 32;
  for (int kt = 0; kt < NK; ++kt) {
    const int buf = kt & 1;
    if (kt + 1 < NK) load(kt + 1);  // global loads: latency hides under MFMA
    bf16x8 af[4], bfv[4];
#pragma unroll
    for (int i = 0; i < 4; ++i) {
      af[i] = *(const bf16x8*)(&As[buf][wm + i * 16 + fr][fk]);
      bfv[i] = *(const bf16x8*)(&Bs[buf][wn + i * 16 + fr][fk]);
    }
#pragma unroll
    for (int i = 0; i < 4; ++i)
#pragma unroll
      for (int j = 0; j < 4; ++j)
        acc[i][j] = __builtin_amdgcn_mfma_f32_16x16x32_bf16(af[i], bfv[j], acc[i][j], 0, 0, 0);
    if (kt + 1 < NK) store(buf ^ 1);  // cvt + LDS write after compute
    __syncthreads();
  }

#pragma unroll
  for (int j = 0; j < 4; ++j) {
    const int n = col0 + wn + j * 16 + fr;
    const float bv = bias[n];
    const int h = n >> 6, d = n & 63;
#pragma unroll
    for (int i = 0; i < 4; ++i) {
      const int mrow = row0 + wm + i * 16 + (lane >> 4) * 4;
#pragma unroll
      for (int r = 0; r < 4; ++r) {
        const int m = mrow + r;
        const int b = m >> 11, t = m & 2047;
        const float val = (acc[i][j][r] + bv) * scale;
        if (vtrans)
          out[(((size_t)b * 16 + h) * 64 + d) * 2048 + t] = f2bf(val);
        else
          out[(((size_t)b * 16 + h) * 2048 + t) * 64 + d] = f2bf(val);
      }
    }
  }
}

// ---------------------------------------------------------------------------
// Output projection: out[m,n] = O[m,:] . Wo[n,:] + bo[n], fp32 out
// A is bf16 (2 chunks, b128 writes, 2-way=free); W fp32 via cvt_pk, T14 split.
// ---------------------------------------------------------------------------
__global__ __launch_bounds__(256) void out_gemm(
    const unsigned short* __restrict__ A, const float* __restrict__ W,
    const float* __restrict__ bias, float* __restrict__ out) {
  const int K = 1024;
  __shared__ __align__(16) unsigned short As[2][128][40];
  __shared__ __align__(16) unsigned short Bs[2][128][40];
  const int tid = threadIdx.x;
  const int row0 = blockIdx.x * 128;
  const int col0 = blockIdx.y * 128;
  const int lane = tid & 63;
  const int wave = tid >> 6;
  const int wm = (wave >> 1) * 64, wn = (wave & 1) * 64;
  const int fr = lane & 15;
  const int fk = (lane >> 4) * 8;

  f32x4 acc[4][4] = {};

  // A staging: chunk c rows c*64 + (tid>>2), col (tid&3)*8 shorts (16B)
  const int ar = tid >> 2;
  const int ac = (tid & 3) * 8;
  // W staging: chunk c rows c*32 + (tid>>3), col (tid&7)*4 floats
  const int sr = tid >> 3;
  const int sc = (tid & 7) * 4;
  const unsigned short* Apt[2];
  const float* Wp[4];
#pragma unroll
  for (int c = 0; c < 2; ++c) Apt[c] = &A[(size_t)(row0 + c * 64 + ar) * K + ac];
#pragma unroll
  for (int c = 0; c < 4; ++c) Wp[c] = &W[(size_t)(col0 + c * 32 + sr) * K + sc];

  uint4 la[2];
  float4 lb[4];
  auto load = [&](int kt) {
    const int k0 = kt * 32;
#pragma unroll
    for (int c = 0; c < 2; ++c) la[c] = *(const uint4*)(Apt[c] + k0);
#pragma unroll
    for (int c = 0; c < 4; ++c) lb[c] = *(const float4*)(Wp[c] + k0);
  };
  auto store = [&](int buf) {
#pragma unroll
    for (int c = 0; c < 2; ++c) *(uint4*)(&As[buf][c * 64 + ar][ac]) = la[c];
#pragma unroll
    for (int c = 0; c < 4; ++c) {
      uint2 ub;
      ub.x = cvtpk_bf16(lb[c].x, lb[c].y); ub.y = cvtpk_bf16(lb[c].z, lb[c].w);
      *(uint2*)(&Bs[buf][c * 32 + sr][sc]) = ub;
    }
  };

  load(0);
  store(0);
  __syncthreads();
  const int NK = K / 32;
  for (int kt = 0; kt < NK; ++kt) {
    const int buf = kt & 1;
    if (kt + 1 < NK) load(kt + 1);
    bf16x8 af[4], bfv[4];
#pragma unroll
    for (int i = 0; i < 4; ++i) {
      af[i] = *(const bf16x8*)(&As[buf][wm + i * 16 + fr][fk]);
      bfv[i] = *(const bf16x8*)(&Bs[buf][wn + i * 16 + fr][fk]);
    }
#pragma unroll
    for (int i = 0; i < 4; ++i)
#pragma unroll
      for (int j = 0; j < 4; ++j)
        acc[i][j] = __builtin_amdgcn_mfma_f32_16x16x32_bf16(af[i], bfv[j], acc[i][j], 0, 0, 0);
    if (kt + 1 < NK) store(buf ^ 1);
    __syncthreads();
  }

#pragma unroll
  for (int j = 0; j < 4; ++j) {
    const int n = col0 + wn + j * 16 + fr;
    const float bv = bias[n];
#pragma unroll
    for (int i = 0; i < 4; ++i) {
      const int mrow = row0 + wm + i * 16 + (lane >> 4) * 4;
#pragma unroll
      for (int r = 0; r < 4; ++r) {
        const int m = mrow + r;
        out[(size_t)m * 1024 + n] = acc[i][j][r] + bv;
      }
    }
  }
}

// ---------------------------------------------------------------------------
// MFMA causal flash attention, 32x32x16, in-register softmax/P-exchange.
// K/V staged via global_load_lds (linear LDS dest, inverse-swizzled global
// source; reads use the same XOR involution). Double-buffered, one barrier
// per tile, loads issued before compute. Defer-max (THR=8, exp2 domain).
// Block = 4 waves; two q-tiles (15-x, x) for uniform 34 tiles/block.
// qh pre-scaled by 0.125*log2(e). Output Ob: bf16 [B][T][C].
// ---------------------------------------------------------------------------
__global__ __launch_bounds__(256) void attn_mfma(
    const unsigned short* __restrict__ qh, const unsigned short* __restrict__ kh,
    const unsigned short* __restrict__ vT, unsigned short* __restrict__ Ob) {
  __shared__ __align__(16) unsigned short Klds[2][64 * 64];
  __shared__ __align__(16) unsigned short Vlds[2][64 * 64];

  const int tid = threadIdx.x;
  const int lane = tid & 63;
  const int w = tid >> 6;
  const int bh = blockIdx.y;
  const int b = bh >> 4, h = bh & 15;
  const int q32 = lane & 31;
  const int hi = lane >> 5;

  const char* kbase = (const char*)(kh + (size_t)bh * 2048 * 64);
  const char* vbase = (const char*)(vT + (size_t)bh * 64 * 2048);

  // per-lane source column (inverse-swizzle): data for LDS slot lane*16 of
  // chunk c lives at global row r=c*8+(lane>>3), col ((lane&7)^(lane>>3))*16
  const int lrow = lane >> 3;
  const int cb = (((lane & 7) ^ lrow) << 4);

  auto stage = [&](int buf, int t) {
    const int kv0 = t * 64;
#pragma unroll
    for (int j = 0; j < 2; ++j) {
      const int c = w * 2 + j;
      const int r = c * 8 + lrow;
      gload_lds16(kbase + (size_t)(kv0 + r) * 128 + cb,
                  (char*)Klds[buf] + c * 1024);
      gload_lds16(vbase + (size_t)r * 4096 + (size_t)kv0 * 2 + cb,
                  (char*)Vlds[buf] + c * 1024);
    }
  };

  for (int pass = 0; pass < 2; ++pass) {
    const int qt = pass == 0 ? (15 - (int)blockIdx.x) : (int)blockIdx.x;
    const int qb = qt * 128 + w * 32;
    const int nt = 2 * qt + 2;

    // Q fragments from global: lane: row q32, d = kk*16 + hi*8 + [0,8)
    bf16x8 qf[4];
    {
      const unsigned short* qp = qh + ((size_t)bh * 2048 + qb + q32) * 64;
#pragma unroll
      for (int kk = 0; kk < 4; ++kk)
        qf[kk] = *(const bf16x8*)(qp + kk * 16 + hi * 8);
    }

    f32x16 acc_o[2] = {};
    float m_run = -INFINITY, l_run = 0.f;

    stage(0, 0);
    __syncthreads();  // drains vmcnt -> buf0 ready

    int cur = 0;
    for (int t = 0; t < nt; ++t) {
      const int kv0 = t * 64;
      if (t + 1 < nt) stage(cur ^ 1, t + 1);  // async, drained by barrier below

      if (kv0 < qb + 32) {  // wave-uniform causal skip
        const char* Kb = (const char*)Klds[cur];
        const char* Vb = (const char*)Vlds[cur];

        // ---- S^T = K @ Q^T ----
        f32x16 sacc[2] = {};
        __builtin_amdgcn_s_setprio(1);
#pragma unroll
        for (int kk = 0; kk < 4; ++kk) {
          bf16x8 kf0 = *(const bf16x8*)(Kb + SWZ((q32) * 128 + kk * 32 + hi * 16));
          bf16x8 kf1 = *(const bf16x8*)(Kb + SWZ((32 + q32) * 128 + kk * 32 + hi * 16));
          sacc[0] = __builtin_amdgcn_mfma_f32_32x32x16_bf16(kf0, qf[kk], sacc[0], 0, 0, 0);
          sacc[1] = __builtin_amdgcn_mfma_f32_32x32x16_bf16(kf1, qf[kk], sacc[1], 0, 0, 0);
        }
        __builtin_amdgcn_s_setprio(0);

        // ---- causal mask on diagonal tiles ----
        if (kv0 + 64 > qb) {
          const int qa = qb + q32;
#pragma unroll
          for (int mkv = 0; mkv < 2; ++mkv)
#pragma unroll
            for (int r = 0; r < 16; ++r) {
              const int kva = kv0 + mkv * 32 + 4 * hi + (r & 3) + 8 * (r >> 2);
              if (kva > qa) sacc[mkv][r] = -INFINITY;
            }
        }

        // ---- online softmax, defer-max (exp2 domain) ----
        float mx = -INFINITY;
#pragma unroll
        for (int mkv = 0; mkv < 2; ++mkv)
#pragma unroll
          for (int r = 0; r < 16; ++r) mx = fmaxf(mx, sacc[mkv][r]);
        mx = fmaxf(mx, __shfl_xor(mx, 32));
        if (!__all(mx <= m_run + 8.f)) {
          const float mnew = fmaxf(m_run, mx);
          const float al = exp2f(m_run - mnew);
          m_run = mnew;
          l_run *= al;
          acc_o[0] = acc_o[0] * al;
          acc_o[1] = acc_o[1] * al;
        }

        float ls = 0.f;
        unsigned W[2][8];
#pragma unroll
        for (int mkv = 0; mkv < 2; ++mkv)
#pragma unroll
          for (int s = 0; s < 8; ++s) {
            const float p0 = exp2f(sacc[mkv][2 * s] - m_run);
            const float p1 = exp2f(sacc[mkv][2 * s + 1] - m_run);
            ls += p0 + p1;
            W[mkv][s] = cvtpk_bf16(p0, p1);
          }
        ls += __shfl_xor(ls, 32);
        l_run += ls;

        // ---- P^T B-frags via permlane32_swap (in place -> j0..j3 order) ----
#pragma unroll
        for (int mkv = 0; mkv < 2; ++mkv) {
          pl32swap(W[mkv][0], W[mkv][2]);
          pl32swap(W[mkv][1], W[mkv][3]);
          pl32swap(W[mkv][4], W[mkv][6]);
          pl32swap(W[mkv][5], W[mkv][7]);
        }

        // ---- O^T += V^T @ P ----
        __builtin_amdgcn_s_setprio(1);
#pragma unroll
        for (int wg = 0; wg < 4; ++wg) {
          union { unsigned u[4]; bf16x8 v; } pk;
          pk.u[0] = W[wg >> 1][(wg & 1) * 4 + 0];
          pk.u[1] = W[wg >> 1][(wg & 1) * 4 + 1];
          pk.u[2] = W[wg >> 1][(wg & 1) * 4 + 2];
          pk.u[3] = W[wg >> 1][(wg & 1) * 4 + 3];
          bf16x8 vf0 = *(const bf16x8*)(Vb + SWZ((q32) * 128 + wg * 32 + hi * 16));
          bf16x8 vf1 = *(const bf16x8*)(Vb + SWZ((32 + q32) * 128 + wg * 32 + hi * 16));
          acc_o[0] = __builtin_amdgcn_mfma_f32_32x32x16_bf16(vf0, pk.v, acc_o[0], 0, 0, 0);
          acc_o[1] = __builtin_amdgcn_mfma_f32_32x32x16_bf16(vf1, pk.v, acc_o[1], 0, 0, 0);
        }
        __builtin_amdgcn_s_setprio(0);
      }

      __syncthreads();  // drains vmcnt(0): next buffer staged & all reads done
      cur ^= 1;
    }

    // ---- epilogue: O^T (row=d, col=q) -> Ob[b][qa][h*64+d] ----
    {
      const float inv = 1.0f / l_run;
      const int qa = qb + q32;
      unsigned short* op = Ob + ((size_t)b * 2048 + qa) * 1024 + h * 64;
#pragma unroll
      for (int md = 0; md < 2; ++md)
#pragma unroll
        for (int rr = 0; rr < 4; ++rr) {
          uint2 u;
          u.x = cvtpk_bf16(acc_o[md][rr * 4 + 0] * inv, acc_o[md][rr * 4 + 1] * inv);
          u.y = cvtpk_bf16(acc_o[md][rr * 4 + 2] * inv, acc_o[md][rr * 4 + 3] * inv);
          *(uint2*)(op + md * 32 + rr * 8 + hi * 4) = u;
        }
    }
  }
}

extern "C" void kernel_launch(void* const* d_in, const int* in_sizes, int n_in,
                              void* d_out, int out_size, void* d_ws, size_t ws_size,
                              hipStream_t stream) {
  (void)in_sizes; (void)n_in; (void)out_size; (void)ws_size;
  const float* q = (const float*)d_in[0];
  const float* k = (const float*)d_in[1];
  const float* v = (const float*)d_in[2];
  const float* Wq = (const float*)d_in[3];
  const float* bq = (const float*)d_in[4];
  const float* Wk = (const float*)d_in[5];
  const float* bk = (const float*)d_in[6];
  const float* Wv = (const float*)d_in[7];
  const float* bv = (const float*)d_in[8];
  const float* Wo = (const float*)d_in[9];
  const float* bo = (const float*)d_in[10];
  float* out = (float*)d_out;

  const size_t SZ = (size_t)4 * 16 * 2048 * 64;  // 8,388,608 elements
  unsigned short* qh = (unsigned short*)d_ws;
  unsigned short* kh = qh + SZ;
  unsigned short* vT = kh + SZ;   // V transposed: [bh][d][t]
  unsigned short* Ob = vT + SZ;   // attention output, [B][T][C] bf16

  dim3 g1(64, 8, 3), b1(256);
  proj_gemm3<<<g1, b1, 0, stream>>>(q, k, v, Wq, Wk, Wv, bq, bk, bv, qh, kh, vT);

  dim3 g2(8, 64), b2(256);
  attn_mfma<<<g2, b2, 0, stream>>>(qh, kh, vT, Ob);

  dim3 g3(64, 8), b3(256);
  out_gemm<<<g3, b3, 0, stream>>>(Ob, Wo, bo, out);
}

// Round 6
// 223.695 us; speedup vs baseline: 8.8751x; 1.0827x over previous
//
#include <hip/hip_runtime.h>
#include <hip/hip_bf16.h>

typedef __attribute__((ext_vector_type(8))) short bf16x8;
typedef __attribute__((ext_vector_type(4))) float f32x4;
typedef __attribute__((ext_vector_type(16))) float f32x16;

__device__ __forceinline__ unsigned short f2bf(float x) {
  union { float f; unsigned u; } v; v.f = x;
  unsigned r = v.u + 0x7fffu + ((v.u >> 16) & 1u);
  return (unsigned short)(r >> 16);
}

__device__ __forceinline__ unsigned cvtpk_bf16(float lo, float hi) {
  unsigned r;
  asm("v_cvt_pk_bf16_f32 %0, %1, %2" : "=v"(r) : "v"(lo), "v"(hi));
  return r;
}
// v_permlane32_swap_b32 a, b : a' = [a_lo, b_lo], b' = [a_hi, b_hi]
__device__ __forceinline__ void pl32swap(unsigned &a, unsigned &b) {
  asm volatile("v_permlane32_swap_b32 %0, %1" : "+v"(a), "+v"(b));
}

__device__ __forceinline__ void gload_lds16(const void* g, void* l) {
  __builtin_amdgcn_global_load_lds((const __attribute__((address_space(1))) void*)g,
                                   (__attribute__((address_space(3))) void*)l, 16, 0, 0);
}

// XOR swizzle for 128-byte-row LDS tiles (attention): flip bits 4-6 by (row&7)
#define SWZ(x) ((x) ^ ((((x) >> 7) & 7) << 4))

// ---------------------------------------------------------------------------
// Weight fp32 -> bf16 pre-convert. z=0 gets scale s0 folded in (Wq).
// 1024x1024 per matrix; grid (1024, 4) x 256 threads x 4 elems.
// ---------------------------------------------------------------------------
__global__ __launch_bounds__(256) void cvt_w(
    const float* __restrict__ W0, const float* __restrict__ W1,
    const float* __restrict__ W2, const float* __restrict__ W3,
    unsigned short* __restrict__ o0, unsigned short* __restrict__ o1,
    unsigned short* __restrict__ o2, unsigned short* __restrict__ o3,
    float s0) {
  const int z = blockIdx.y;
  const float* W = (z == 0) ? W0 : (z == 1) ? W1 : (z == 2) ? W2 : W3;
  unsigned short* o = (z == 0) ? o0 : (z == 1) ? o1 : (z == 2) ? o2 : o3;
  const float s = (z == 0) ? s0 : 1.0f;
  const int i = blockIdx.x * 256 + threadIdx.x;
  const float4 x = ((const float4*)W)[i];
  uint2 u;
  u.x = cvtpk_bf16(x.x * s, x.y * s);
  u.y = cvtpk_bf16(x.z * s, x.w * s);
  ((uint2*)o)[i] = u;
}

// ===========================================================================
// GEMM LDS layout (tile [128 rows][32 k] bf16, 8KB):
//   row pair p = r>>1, 16B chunk c (0..3), gc = ((r&1)*4 + c) ^ (p&7)
//   byte addr = p*128 + gc*16.
// Verified: every 8-lane read phase and every write phase hits all 32 banks
// exactly once (conflict-free). gload_lds writes the 512 chunks linearly:
// chunk L -> p=L>>3, gc=L&7, source (r,c) from e = gc ^ (p&7).
// ===========================================================================

// ---------------------------------------------------------------------------
// Merged Q/K/V projection GEMM. z: 0=Q (Wq pre-scaled), 1=K, 2=V(transposed).
// A fp32 reg-staged (cvt_pk, swizzled b128 writes); B bf16 via global_load_lds.
// ---------------------------------------------------------------------------
__global__ __launch_bounds__(256) void proj_gemm3(
    const float* __restrict__ A0, const float* __restrict__ A1, const float* __restrict__ A2,
    const unsigned short* __restrict__ W0b, const unsigned short* __restrict__ W1b,
    const unsigned short* __restrict__ W2b,
    const float* __restrict__ b0, const float* __restrict__ b1, const float* __restrict__ b2,
    unsigned short* __restrict__ o0, unsigned short* __restrict__ o1,
    unsigned short* __restrict__ o2) {
  const int K = 1024;
  __shared__ __align__(16) unsigned short As[2][4096];
  __shared__ __align__(16) unsigned short Bs[2][4096];
  const int z = blockIdx.z;
  const float* A = (z == 0) ? A0 : (z == 1) ? A1 : A2;
  const unsigned short* Wb = (z == 0) ? W0b : (z == 1) ? W1b : W2b;
  const float* bias = (z == 0) ? b0 : (z == 1) ? b1 : b2;
  unsigned short* out = (z == 0) ? o0 : (z == 1) ? o1 : o2;
  const float bscale = (z == 0) ? 0.125f * 1.4426950408889634f : 1.0f;
  const int vtrans = (z == 2);

  const int tid = threadIdx.x;
  const int row0 = blockIdx.x * 128;
  const int col0 = blockIdx.y * 128;
  const int lane = tid & 63;
  const int w = tid >> 6;
  const int wm = (w >> 1) * 64, wn = (w & 1) * 64;
  const int fr = lane & 15;
  const int g = lane >> 4;
  const int frh = fr >> 1;
  const int gcf = ((fr & 1) * 4 + g) ^ frh;
  const int aoff = wm * 64 + frh * 128 + gcf * 16;  // frag byte offset, +i*1024
  const int boff = wn * 64 + frh * 128 + gcf * 16;

  // A staging: thread covers rows ar, ar+64; fp32 cols acq*8..+7
  const int ar = tid >> 2;
  const int acq = tid & 3;
  const float* asrc0 = &A[(size_t)(row0 + ar) * K + acq * 8];
  const float* asrc1 = asrc0 + (size_t)64 * K;
  const int awr = (ar >> 1) * 128 + ((((ar & 1) * 4 + acq) ^ ((ar >> 1) & 7)) * 16);

  // B staging via gload: wave w, instr j -> chunks L=(w*2+j)*64+lane
  const unsigned short* bsrc[2];
  int bldso[2];
#pragma unroll
  for (int j = 0; j < 2; ++j) {
    const int L = (w * 2 + j) * 64 + lane;
    const int pp = L >> 3, gc = L & 7;
    const int e = gc ^ (pp & 7);
    const int r = pp * 2 + (e >> 2), c = e & 3;
    bsrc[j] = Wb + (size_t)(col0 + r) * K + c * 8;
    bldso[j] = (w * 2 + j) * 1024;  // wave-uniform byte base (HW adds lane*16)
  }

  f32x4 acc[4][4] = {};
  float4 la[4];

  auto loadA = [&](int kt) {
    const float* s0 = asrc0 + kt * 32;
    const float* s1 = asrc1 + kt * 32;
    la[0] = *(const float4*)s0; la[1] = *(const float4*)(s0 + 4);
    la[2] = *(const float4*)s1; la[3] = *(const float4*)(s1 + 4);
  };
  auto storeA = [&](int buf) {
    uint4 u0, u1;
    u0.x = cvtpk_bf16(la[0].x, la[0].y); u0.y = cvtpk_bf16(la[0].z, la[0].w);
    u0.z = cvtpk_bf16(la[1].x, la[1].y); u0.w = cvtpk_bf16(la[1].z, la[1].w);
    u1.x = cvtpk_bf16(la[2].x, la[2].y); u1.y = cvtpk_bf16(la[2].z, la[2].w);
    u1.z = cvtpk_bf16(la[3].x, la[3].y); u1.w = cvtpk_bf16(la[3].z, la[3].w);
    char* base = (char*)As[buf];
    *(uint4*)(base + awr) = u0;
    *(uint4*)(base + awr + 4096) = u1;  // row+64 -> pair+32 -> +4KB, same gc
  };
  auto stageB = [&](int buf, int kt) {
#pragma unroll
    for (int j = 0; j < 2; ++j)
      gload_lds16(bsrc[j] + kt * 32, (char*)Bs[buf] + bldso[j]);
  };

  loadA(0); stageB(0, 0); storeA(0);
  __syncthreads();
  for (int kt = 0; kt < 32; ++kt) {
    const int buf = kt & 1;
    if (kt < 31) { loadA(kt + 1); stageB(buf ^ 1, kt + 1); }
    const char* Ab = (const char*)As[buf];
    const char* Bb = (const char*)Bs[buf];
    bf16x8 af[4], bfv[4];
#pragma unroll
    for (int i = 0; i < 4; ++i) {
      af[i] = *(const bf16x8*)(Ab + aoff + i * 1024);
      bfv[i] = *(const bf16x8*)(Bb + boff + i * 1024);
    }
#pragma unroll
    for (int i = 0; i < 4; ++i)
#pragma unroll
      for (int j = 0; j < 4; ++j)
        acc[i][j] = __builtin_amdgcn_mfma_f32_16x16x32_bf16(af[i], bfv[j], acc[i][j], 0, 0, 0);
    if (kt < 31) storeA(buf ^ 1);
    __syncthreads();
  }

#pragma unroll
  for (int j = 0; j < 4; ++j) {
    const int n = col0 + wn + j * 16 + fr;
    const float bv = bias[n] * bscale;
    const int h = n >> 6, d = n & 63;
#pragma unroll
    for (int i = 0; i < 4; ++i) {
      const int mrow = row0 + wm + i * 16 + g * 4;
      const int b = mrow >> 11, t0 = mrow & 2047;
      if (vtrans) {
        uint2 u;
        u.x = cvtpk_bf16(acc[i][j][0] + bv, acc[i][j][1] + bv);
        u.y = cvtpk_bf16(acc[i][j][2] + bv, acc[i][j][3] + bv);
        *(uint2*)(&out[(((size_t)b * 16 + h) * 64 + d) * 2048 + t0]) = u;
      } else {
#pragma unroll
        for (int r = 0; r < 4; ++r)
          out[(((size_t)b * 16 + h) * 2048 + (t0 + r)) * 64 + d] = f2bf(acc[i][j][r] + bv);
      }
    }
  }
}

// ---------------------------------------------------------------------------
// Output projection: both operands bf16, pure global_load_lds staging.
// out[m,n] = O[m,:] . Wo[n,:] + bo[n], fp32 out.
// ---------------------------------------------------------------------------
__global__ __launch_bounds__(256) void out_gemm(
    const unsigned short* __restrict__ A, const unsigned short* __restrict__ Wb,
    const float* __restrict__ bias, float* __restrict__ out) {
  const int K = 1024;
  __shared__ __align__(16) unsigned short As[2][4096];
  __shared__ __align__(16) unsigned short Bs[2][4096];
  const int tid = threadIdx.x;
  const int row0 = blockIdx.x * 128;
  const int col0 = blockIdx.y * 128;
  const int lane = tid & 63;
  const int w = tid >> 6;
  const int wm = (w >> 1) * 64, wn = (w & 1) * 64;
  const int fr = lane & 15;
  const int g = lane >> 4;
  const int frh = fr >> 1;
  const int gcf = ((fr & 1) * 4 + g) ^ frh;
  const int aoff = wm * 64 + frh * 128 + gcf * 16;
  const int boff = wn * 64 + frh * 128 + gcf * 16;

  const unsigned short* asrc[2];
  const unsigned short* bsrc[2];
  int ldso[2];
#pragma unroll
  for (int j = 0; j < 2; ++j) {
    const int L = (w * 2 + j) * 64 + lane;
    const int pp = L >> 3, gc = L & 7;
    const int e = gc ^ (pp & 7);
    const int r = pp * 2 + (e >> 2), c = e & 3;
    asrc[j] = A + (size_t)(row0 + r) * K + c * 8;
    bsrc[j] = Wb + (size_t)(col0 + r) * K + c * 8;
    ldso[j] = (w * 2 + j) * 1024;
  }

  f32x4 acc[4][4] = {};

  auto stage = [&](int buf, int kt) {
#pragma unroll
    for (int j = 0; j < 2; ++j) {
      gload_lds16(asrc[j] + kt * 32, (char*)As[buf] + ldso[j]);
      gload_lds16(bsrc[j] + kt * 32, (char*)Bs[buf] + ldso[j]);
    }
  };

  stage(0, 0);
  __syncthreads();
  for (int kt = 0; kt < 32; ++kt) {
    const int buf = kt & 1;
    if (kt < 31) stage(buf ^ 1, kt + 1);
    const char* Ab = (const char*)As[buf];
    const char* Bb = (const char*)Bs[buf];
    bf16x8 af[4], bfv[4];
#pragma unroll
    for (int i = 0; i < 4; ++i) {
      af[i] = *(const bf16x8*)(Ab + aoff + i * 1024);
      bfv[i] = *(const bf16x8*)(Bb + boff + i * 1024);
    }
#pragma unroll
    for (int i = 0; i < 4; ++i)
#pragma unroll
      for (int j = 0; j < 4; ++j)
        acc[i][j] = __builtin_amdgcn_mfma_f32_16x16x32_bf16(af[i], bfv[j], acc[i][j], 0, 0, 0);
    __syncthreads();
  }

#pragma unroll
  for (int j = 0; j < 4; ++j) {
    const int n = col0 + wn + j * 16 + fr;
    const float bv = bias[n];
#pragma unroll
    for (int i = 0; i < 4; ++i) {
      const int mrow = row0 + wm + i * 16 + g * 4;
#pragma unroll
      for (int r = 0; r < 4; ++r)
        out[(size_t)(mrow + r) * 1024 + n] = acc[i][j][r] + bv;
    }
  }
}

// ---------------------------------------------------------------------------
// MFMA causal flash attention (unchanged from R5): 32x32x16, in-register
// softmax/P-exchange, gload_lds K/V staging, defer-max, setprio.
// ---------------------------------------------------------------------------
__global__ __launch_bounds__(256) void attn_mfma(
    const unsigned short* __restrict__ qh, const unsigned short* __restrict__ kh,
    const unsigned short* __restrict__ vT, unsigned short* __restrict__ Ob) {
  __shared__ __align__(16) unsigned short Klds[2][64 * 64];
  __shared__ __align__(16) unsigned short Vlds[2][64 * 64];

  const int tid = threadIdx.x;
  const int lane = tid & 63;
  const int w = tid >> 6;
  const int bh = blockIdx.y;
  const int b = bh >> 4, h = bh & 15;
  const int q32 = lane & 31;
  const int hi = lane >> 5;

  const char* kbase = (const char*)(kh + (size_t)bh * 2048 * 64);
  const char* vbase = (const char*)(vT + (size_t)bh * 64 * 2048);

  const int lrow = lane >> 3;
  const int cb = (((lane & 7) ^ lrow) << 4);

  auto stage = [&](int buf, int t) {
    const int kv0 = t * 64;
#pragma unroll
    for (int j = 0; j < 2; ++j) {
      const int c = w * 2 + j;
      const int r = c * 8 + lrow;
      gload_lds16(kbase + (size_t)(kv0 + r) * 128 + cb,
                  (char*)Klds[buf] + c * 1024);
      gload_lds16(vbase + (size_t)r * 4096 + (size_t)kv0 * 2 + cb,
                  (char*)Vlds[buf] + c * 1024);
    }
  };

  for (int pass = 0; pass < 2; ++pass) {
    const int qt = pass == 0 ? (15 - (int)blockIdx.x) : (int)blockIdx.x;
    const int qb = qt * 128 + w * 32;
    const int nt = 2 * qt + 2;

    bf16x8 qf[4];
    {
      const unsigned short* qp = qh + ((size_t)bh * 2048 + qb + q32) * 64;
#pragma unroll
      for (int kk = 0; kk < 4; ++kk)
        qf[kk] = *(const bf16x8*)(qp + kk * 16 + hi * 8);
    }

    f32x16 acc_o[2] = {};
    float m_run = -INFINITY, l_run = 0.f;

    stage(0, 0);
    __syncthreads();

    int cur = 0;
    for (int t = 0; t < nt; ++t) {
      const int kv0 = t * 64;
      if (t + 1 < nt) stage(cur ^ 1, t + 1);

      if (kv0 < qb + 32) {
        const char* Kb = (const char*)Klds[cur];
        const char* Vb = (const char*)Vlds[cur];

        f32x16 sacc[2] = {};
        __builtin_amdgcn_s_setprio(1);
#pragma unroll
        for (int kk = 0; kk < 4; ++kk) {
          bf16x8 kf0 = *(const bf16x8*)(Kb + SWZ((q32) * 128 + kk * 32 + hi * 16));
          bf16x8 kf1 = *(const bf16x8*)(Kb + SWZ((32 + q32) * 128 + kk * 32 + hi * 16));
          sacc[0] = __builtin_amdgcn_mfma_f32_32x32x16_bf16(kf0, qf[kk], sacc[0], 0, 0, 0);
          sacc[1] = __builtin_amdgcn_mfma_f32_32x32x16_bf16(kf1, qf[kk], sacc[1], 0, 0, 0);
        }
        __builtin_amdgcn_s_setprio(0);

        if (kv0 + 64 > qb) {
          const int qa = qb + q32;
#pragma unroll
          for (int mkv = 0; mkv < 2; ++mkv)
#pragma unroll
            for (int r = 0; r < 16; ++r) {
              const int kva = kv0 + mkv * 32 + 4 * hi + (r & 3) + 8 * (r >> 2);
              if (kva > qa) sacc[mkv][r] = -INFINITY;
            }
        }

        float mx = -INFINITY;
#pragma unroll
        for (int mkv = 0; mkv < 2; ++mkv)
#pragma unroll
          for (int r = 0; r < 16; ++r) mx = fmaxf(mx, sacc[mkv][r]);
        mx = fmaxf(mx, __shfl_xor(mx, 32));
        if (!__all(mx <= m_run + 8.f)) {
          const float mnew = fmaxf(m_run, mx);
          const float al = exp2f(m_run - mnew);
          m_run = mnew;
          l_run *= al;
          acc_o[0] = acc_o[0] * al;
          acc_o[1] = acc_o[1] * al;
        }

        float ls = 0.f;
        unsigned W[2][8];
#pragma unroll
        for (int mkv = 0; mkv < 2; ++mkv)
#pragma unroll
          for (int s = 0; s < 8; ++s) {
            const float p0 = exp2f(sacc[mkv][2 * s] - m_run);
            const float p1 = exp2f(sacc[mkv][2 * s + 1] - m_run);
            ls += p0 + p1;
            W[mkv][s] = cvtpk_bf16(p0, p1);
          }
        ls += __shfl_xor(ls, 32);
        l_run += ls;

#pragma unroll
        for (int mkv = 0; mkv < 2; ++mkv) {
          pl32swap(W[mkv][0], W[mkv][2]);
          pl32swap(W[mkv][1], W[mkv][3]);
          pl32swap(W[mkv][4], W[mkv][6]);
          pl32swap(W[mkv][5], W[mkv][7]);
        }

        __builtin_amdgcn_s_setprio(1);
#pragma unroll
        for (int wg = 0; wg < 4; ++wg) {
          union { unsigned u[4]; bf16x8 v; } pk;
          pk.u[0] = W[wg >> 1][(wg & 1) * 4 + 0];
          pk.u[1] = W[wg >> 1][(wg & 1) * 4 + 1];
          pk.u[2] = W[wg >> 1][(wg & 1) * 4 + 2];
          pk.u[3] = W[wg >> 1][(wg & 1) * 4 + 3];
          bf16x8 vf0 = *(const bf16x8*)(Vb + SWZ((q32) * 128 + wg * 32 + hi * 16));
          bf16x8 vf1 = *(const bf16x8*)(Vb + SWZ((32 + q32) * 128 + wg * 32 + hi * 16));
          acc_o[0] = __builtin_amdgcn_mfma_f32_32x32x16_bf16(vf0, pk.v, acc_o[0], 0, 0, 0);
          acc_o[1] = __builtin_amdgcn_mfma_f32_32x32x16_bf16(vf1, pk.v, acc_o[1], 0, 0, 0);
        }
        __builtin_amdgcn_s_setprio(0);
      }

      __syncthreads();
      cur ^= 1;
    }

    {
      const float inv = 1.0f / l_run;
      const int qa = qb + q32;
      unsigned short* op = Ob + ((size_t)b * 2048 + qa) * 1024 + h * 64;
#pragma unroll
      for (int md = 0; md < 2; ++md)
#pragma unroll
        for (int rr = 0; rr < 4; ++rr) {
          uint2 u;
          u.x = cvtpk_bf16(acc_o[md][rr * 4 + 0] * inv, acc_o[md][rr * 4 + 1] * inv);
          u.y = cvtpk_bf16(acc_o[md][rr * 4 + 2] * inv, acc_o[md][rr * 4 + 3] * inv);
          *(uint2*)(op + md * 32 + rr * 8 + hi * 4) = u;
        }
    }
  }
}

extern "C" void kernel_launch(void* const* d_in, const int* in_sizes, int n_in,
                              void* d_out, int out_size, void* d_ws, size_t ws_size,
                              hipStream_t stream) {
  (void)in_sizes; (void)n_in; (void)out_size; (void)ws_size;
  const float* q = (const float*)d_in[0];
  const float* k = (const float*)d_in[1];
  const float* v = (const float*)d_in[2];
  const float* Wq = (const float*)d_in[3];
  const float* bq = (const float*)d_in[4];
  const float* Wk = (const float*)d_in[5];
  const float* bk = (const float*)d_in[6];
  const float* Wv = (const float*)d_in[7];
  const float* bv = (const float*)d_in[8];
  const float* Wo = (const float*)d_in[9];
  const float* bo = (const float*)d_in[10];
  float* out = (float*)d_out;

  const size_t SZ = (size_t)4 * 16 * 2048 * 64;   // 8,388,608 elements
  const size_t WSZ = (size_t)1024 * 1024;         // 1,048,576 elements
  unsigned short* qh = (unsigned short*)d_ws;
  unsigned short* kh = qh + SZ;
  unsigned short* vT = kh + SZ;    // V transposed: [bh][d][t]
  unsigned short* Ob = vT + SZ;    // attention output, [B][T][C] bf16
  unsigned short* Wqb = Ob + SZ;   // bf16 weights (Wq pre-scaled)
  unsigned short* Wkb = Wqb + WSZ;
  unsigned short* Wvb = Wkb + WSZ;
  unsigned short* Wob = Wvb + WSZ;

  dim3 g0(1024, 4), b0(256);
  cvt_w<<<g0, b0, 0, stream>>>(Wq, Wk, Wv, Wo, Wqb, Wkb, Wvb, Wob,
                               0.125f * 1.4426950408889634f);

  dim3 g1(64, 8, 3), b1(256);
  proj_gemm3<<<g1, b1, 0, stream>>>(q, k, v, Wqb, Wkb, Wvb, bq, bk, bv, qh, kh, vT);

  dim3 g2(8, 64), b2(256);
  attn_mfma<<<g2, b2, 0, stream>>>(qh, kh, vT, Ob);

  dim3 g3(64, 8), b3(256);
  out_gemm<<<g3, b3, 0, stream>>>(Ob, Wob, bo, out);
}

// Round 7
// 201.171 us; speedup vs baseline: 9.8687x; 1.1120x over previous
//
#include <hip/hip_runtime.h>
#include <hip/hip_bf16.h>

typedef __attribute__((ext_vector_type(8))) short bf16x8;
typedef __attribute__((ext_vector_type(4))) float f32x4;
typedef __attribute__((ext_vector_type(16))) float f32x16;

__device__ __forceinline__ unsigned short f2bf(float x) {
  union { float f; unsigned u; } v; v.f = x;
  unsigned r = v.u + 0x7fffu + ((v.u >> 16) & 1u);
  return (unsigned short)(r >> 16);
}

__device__ __forceinline__ unsigned cvtpk_bf16(float lo, float hi) {
  unsigned r;
  asm("v_cvt_pk_bf16_f32 %0, %1, %2" : "=v"(r) : "v"(lo), "v"(hi));
  return r;
}
__device__ __forceinline__ void pl32swap(unsigned &a, unsigned &b) {
  asm volatile("v_permlane32_swap_b32 %0, %1" : "+v"(a), "+v"(b));
}
__device__ __forceinline__ void gload_lds16(const void* g, void* l) {
  __builtin_amdgcn_global_load_lds((const __attribute__((address_space(1))) void*)g,
                                   (__attribute__((address_space(3))) void*)l, 16, 0, 0);
}

#define SWZ(x) ((x) ^ ((((x) >> 7) & 7) << 4))

// ---------------------------------------------------------------------------
// Weight fp32 -> bf16 pre-convert (Wq scaled by s0).
// ---------------------------------------------------------------------------
__global__ __launch_bounds__(256) void cvt_w(
    const float* __restrict__ W0, const float* __restrict__ W1,
    const float* __restrict__ W2, const float* __restrict__ W3,
    unsigned short* __restrict__ o0, unsigned short* __restrict__ o1,
    unsigned short* __restrict__ o2, unsigned short* __restrict__ o3,
    float s0) {
  const int z = blockIdx.y;
  const float* W = (z == 0) ? W0 : (z == 1) ? W1 : (z == 2) ? W2 : W3;
  unsigned short* o = (z == 0) ? o0 : (z == 1) ? o1 : (z == 2) ? o2 : o3;
  const float s = (z == 0) ? s0 : 1.0f;
  const int i = blockIdx.x * 256 + threadIdx.x;
  const float4 x = ((const float4*)W)[i];
  uint2 u;
  u.x = cvtpk_bf16(x.x * s, x.y * s);
  u.y = cvtpk_bf16(x.z * s, x.w * s);
  ((uint2*)o)[i] = u;
}

// ===========================================================================
// GEMM LDS layout per 8KB buffer (tile [128 rows][32 k] bf16):
//   row pair p = r>>1, 16B chunk c (0..3), gc = ((r&1)*4 + c) ^ (p&7)
//   byte addr = p*128 + gc*16. Conflict-free reads and writes (verified R6:
//   SQ_LDS_BANK_CONFLICT == 0).
// Pipeline: 3-deep LDS ring, counted vmcnt (T4), raw s_barrier, one barrier
// per K-step. stage(t+2) issued at step t; top-of-step waits leave the last
// step's loads in flight.
// ===========================================================================

// ---------------------------------------------------------------------------
// Merged Q/K/V projection GEMM. z: 0=Q (Wq pre-scaled), 1=K, 2=V(transposed).
// A fp32 reg-staged (la0/la1 ping-pong, cvt_pk, swizzled b128 writes);
// B bf16 via global_load_lds.
// ---------------------------------------------------------------------------
__global__ __launch_bounds__(256) void proj_gemm3(
    const float* __restrict__ A0, const float* __restrict__ A1, const float* __restrict__ A2,
    const unsigned short* __restrict__ W0b, const unsigned short* __restrict__ W1b,
    const unsigned short* __restrict__ W2b,
    const float* __restrict__ b0, const float* __restrict__ b1, const float* __restrict__ b2,
    unsigned short* __restrict__ o0, unsigned short* __restrict__ o1,
    unsigned short* __restrict__ o2) {
  const int K = 1024;
  const int NK = 32;
  __shared__ __align__(16) unsigned short As[3][4096];
  __shared__ __align__(16) unsigned short Bs[3][4096];
  const int z = blockIdx.z;
  const float* A = (z == 0) ? A0 : (z == 1) ? A1 : A2;
  const unsigned short* Wb = (z == 0) ? W0b : (z == 1) ? W1b : W2b;
  const float* bias = (z == 0) ? b0 : (z == 1) ? b1 : b2;
  unsigned short* out = (z == 0) ? o0 : (z == 1) ? o1 : o2;
  const float bscale = (z == 0) ? 0.125f * 1.4426950408889634f : 1.0f;
  const int vtrans = (z == 2);

  const int tid = threadIdx.x;
  const int row0 = blockIdx.x * 128;
  const int col0 = blockIdx.y * 128;
  const int lane = tid & 63;
  const int w = tid >> 6;
  const int wm = (w >> 1) * 64, wn = (w & 1) * 64;
  const int fr = lane & 15;
  const int g = lane >> 4;
  const int frh = fr >> 1;
  const int gcf = ((fr & 1) * 4 + g) ^ frh;
  const int aoff = wm * 64 + frh * 128 + gcf * 16;
  const int boff = wn * 64 + frh * 128 + gcf * 16;

  // A staging: thread covers rows ar, ar+64; fp32 cols acq*8..+7
  const int ar = tid >> 2;
  const int acq = tid & 3;
  const float* asrc0 = &A[(size_t)(row0 + ar) * K + acq * 8];
  const float* asrc1 = asrc0 + (size_t)64 * K;
  const int awr = (ar >> 1) * 128 + ((((ar & 1) * 4 + acq) ^ ((ar >> 1) & 7)) * 16);

  // B staging via gload_lds (inverse-swizzled source, linear LDS dest)
  const unsigned short* bsrc[2];
  int bldso[2];
#pragma unroll
  for (int j = 0; j < 2; ++j) {
    const int L = (w * 2 + j) * 64 + lane;
    const int pp = L >> 3, gc = L & 7;
    const int e = gc ^ (pp & 7);
    const int r = pp * 2 + (e >> 2), c = e & 3;
    bsrc[j] = Wb + (size_t)(col0 + r) * K + c * 8;
    bldso[j] = (w * 2 + j) * 1024;
  }

  f32x4 acc[4][4] = {};
  float4 la0[4], la1[4];

#define LOADA(kt, LA)                                        \
  {                                                          \
    const float* s0_ = asrc0 + (kt) * 32;                    \
    const float* s1_ = asrc1 + (kt) * 32;                    \
    LA[0] = *(const float4*)s0_; LA[1] = *(const float4*)(s0_ + 4); \
    LA[2] = *(const float4*)s1_; LA[3] = *(const float4*)(s1_ + 4); \
  }
#define STOREA(buf, LA)                                               \
  {                                                                   \
    uint4 u0_, u1_;                                                   \
    u0_.x = cvtpk_bf16(LA[0].x, LA[0].y); u0_.y = cvtpk_bf16(LA[0].z, LA[0].w); \
    u0_.z = cvtpk_bf16(LA[1].x, LA[1].y); u0_.w = cvtpk_bf16(LA[1].z, LA[1].w); \
    u1_.x = cvtpk_bf16(LA[2].x, LA[2].y); u1_.y = cvtpk_bf16(LA[2].z, LA[2].w); \
    u1_.z = cvtpk_bf16(LA[3].x, LA[3].y); u1_.w = cvtpk_bf16(LA[3].z, LA[3].w); \
    char* base_ = (char*)As[buf];                                     \
    *(uint4*)(base_ + awr) = u0_;                                     \
    *(uint4*)(base_ + awr + 4096) = u1_;                              \
  }
#define STAGEB(buf, kt)                                               \
  {                                                                   \
    gload_lds16(bsrc[0] + (kt) * 32, (char*)Bs[buf] + bldso[0]);      \
    gload_lds16(bsrc[1] + (kt) * 32, (char*)Bs[buf] + bldso[1]);      \
  }
#define COMPUTE(cb)                                                   \
  {                                                                   \
    const char* Ab_ = (const char*)As[cb];                            \
    const char* Bb_ = (const char*)Bs[cb];                            \
    bf16x8 af[4], bfv[4];                                             \
    _Pragma("unroll")                                                 \
    for (int i = 0; i < 4; ++i) {                                     \
      af[i] = *(const bf16x8*)(Ab_ + aoff + i * 1024);                \
      bfv[i] = *(const bf16x8*)(Bb_ + boff + i * 1024);               \
    }                                                                 \
    _Pragma("unroll")                                                 \
    for (int i = 0; i < 4; ++i)                                       \
      _Pragma("unroll")                                               \
      for (int j = 0; j < 4; ++j)                                     \
        acc[i][j] = __builtin_amdgcn_mfma_f32_16x16x32_bf16(af[i], bfv[j], acc[i][j], 0, 0, 0); \
  }

  // prologue: B0,B1 in flight; A0 staged to LDS, A1 in regs
  STAGEB(0, 0); STAGEB(1, 1);
  LOADA(0, la0); LOADA(1, la1);
  STOREA(0, la0);
  asm volatile("s_waitcnt lgkmcnt(0)" ::: "memory");

  int cur = 0;
  for (int kt = 0; kt < NK; kt += 2) {
    // ---------- even sub-step: consume buf[cur], load->la0, store la1 ----
    if (kt == 0) asm volatile("s_waitcnt vmcnt(0)" ::: "memory");
    else         asm volatile("s_waitcnt vmcnt(6)" ::: "memory");
    __builtin_amdgcn_sched_barrier(0);
    __builtin_amdgcn_s_barrier();
    __builtin_amdgcn_sched_barrier(0);
    {
      const int nx1 = (cur == 2) ? 0 : cur + 1;
      const int nx2 = (nx1 == 2) ? 0 : nx1 + 1;
      if (kt + 2 < NK) { LOADA(kt + 2, la0); STAGEB(nx2, kt + 2); }
      __builtin_amdgcn_sched_barrier(0);
      COMPUTE(cur);
      STOREA(nx1, la1);  // A(kt+1) -> next buffer
      asm volatile("s_waitcnt lgkmcnt(0)" ::: "memory");
      cur = nx1;
    }
    // ---------- odd sub-step: consume buf[cur], load->la1, store la0 -----
    if (kt + 1 == NK - 1) asm volatile("s_waitcnt vmcnt(0)" ::: "memory");
    else                  asm volatile("s_waitcnt vmcnt(6)" ::: "memory");
    __builtin_amdgcn_sched_barrier(0);
    __builtin_amdgcn_s_barrier();
    __builtin_amdgcn_sched_barrier(0);
    {
      const int nx1 = (cur == 2) ? 0 : cur + 1;
      const int nx2 = (nx1 == 2) ? 0 : nx1 + 1;
      if (kt + 3 < NK) { LOADA(kt + 3, la1); STAGEB(nx2, kt + 3); }
      __builtin_amdgcn_sched_barrier(0);
      COMPUTE(cur);
      if (kt + 2 < NK) {
        STOREA(nx1, la0);  // A(kt+2) -> next buffer
        asm volatile("s_waitcnt lgkmcnt(0)" ::: "memory");
      }
      cur = nx1;
    }
  }
#undef LOADA
#undef STOREA
#undef STAGEB
#undef COMPUTE

#pragma unroll
  for (int j = 0; j < 4; ++j) {
    const int n = col0 + wn + j * 16 + fr;
    const float bv = bias[n] * bscale;
    const int h = n >> 6, d = n & 63;
#pragma unroll
    for (int i = 0; i < 4; ++i) {
      const int mrow = row0 + wm + i * 16 + g * 4;
      const int b = mrow >> 11, t0 = mrow & 2047;
      if (vtrans) {
        uint2 u;
        u.x = cvtpk_bf16(acc[i][j][0] + bv, acc[i][j][1] + bv);
        u.y = cvtpk_bf16(acc[i][j][2] + bv, acc[i][j][3] + bv);
        *(uint2*)(&out[(((size_t)b * 16 + h) * 64 + d) * 2048 + t0]) = u;
      } else {
#pragma unroll
        for (int r = 0; r < 4; ++r)
          out[(((size_t)b * 16 + h) * 2048 + (t0 + r)) * 64 + d] = f2bf(acc[i][j][r] + bv);
      }
    }
  }
}

// ---------------------------------------------------------------------------
// Output projection: both operands bf16, pure gload_lds, ring-3 counted vmcnt.
// ---------------------------------------------------------------------------
__global__ __launch_bounds__(256) void out_gemm(
    const unsigned short* __restrict__ A, const unsigned short* __restrict__ Wb,
    const float* __restrict__ bias, float* __restrict__ out) {
  const int K = 1024;
  const int NK = 32;
  __shared__ __align__(16) unsigned short As[3][4096];
  __shared__ __align__(16) unsigned short Bs[3][4096];
  const int tid = threadIdx.x;
  const int row0 = blockIdx.x * 128;
  const int col0 = blockIdx.y * 128;
  const int lane = tid & 63;
  const int w = tid >> 6;
  const int wm = (w >> 1) * 64, wn = (w & 1) * 64;
  const int fr = lane & 15;
  const int g = lane >> 4;
  const int frh = fr >> 1;
  const int gcf = ((fr & 1) * 4 + g) ^ frh;
  const int aoff = wm * 64 + frh * 128 + gcf * 16;
  const int boff = wn * 64 + frh * 128 + gcf * 16;

  const unsigned short* asrc[2];
  const unsigned short* bsrc[2];
  int ldso[2];
#pragma unroll
  for (int j = 0; j < 2; ++j) {
    const int L = (w * 2 + j) * 64 + lane;
    const int pp = L >> 3, gc = L & 7;
    const int e = gc ^ (pp & 7);
    const int r = pp * 2 + (e >> 2), c = e & 3;
    asrc[j] = A + (size_t)(row0 + r) * K + c * 8;
    bsrc[j] = Wb + (size_t)(col0 + r) * K + c * 8;
    ldso[j] = (w * 2 + j) * 1024;
  }

  f32x4 acc[4][4] = {};

  auto stage = [&](int buf, int kt) {
#pragma unroll
    for (int j = 0; j < 2; ++j) {
      gload_lds16(asrc[j] + kt * 32, (char*)As[buf] + ldso[j]);
      gload_lds16(bsrc[j] + kt * 32, (char*)Bs[buf] + ldso[j]);
    }
  };

  stage(0, 0); stage(1, 1);
  int cur = 0;
  for (int kt = 0; kt < NK; ++kt) {
    if (kt == 0 || kt == NK - 1) asm volatile("s_waitcnt vmcnt(0)" ::: "memory");
    else                         asm volatile("s_waitcnt vmcnt(4)" ::: "memory");
    __builtin_amdgcn_sched_barrier(0);
    __builtin_amdgcn_s_barrier();
    __builtin_amdgcn_sched_barrier(0);
    const int nx1 = (cur == 2) ? 0 : cur + 1;
    const int nx2 = (nx1 == 2) ? 0 : nx1 + 1;
    if (kt + 2 < NK) stage(nx2, kt + 2);
    __builtin_amdgcn_sched_barrier(0);
    const char* Ab = (const char*)As[cur];
    const char* Bb = (const char*)Bs[cur];
    bf16x8 af[4], bfv[4];
#pragma unroll
    for (int i = 0; i < 4; ++i) {
      af[i] = *(const bf16x8*)(Ab + aoff + i * 1024);
      bfv[i] = *(const bf16x8*)(Bb + boff + i * 1024);
    }
#pragma unroll
    for (int i = 0; i < 4; ++i)
#pragma unroll
      for (int j = 0; j < 4; ++j)
        acc[i][j] = __builtin_amdgcn_mfma_f32_16x16x32_bf16(af[i], bfv[j], acc[i][j], 0, 0, 0);
    cur = nx1;
  }

#pragma unroll
  for (int j = 0; j < 4; ++j) {
    const int n = col0 + wn + j * 16 + fr;
    const float bv = bias[n];
#pragma unroll
    for (int i = 0; i < 4; ++i) {
      const int mrow = row0 + wm + i * 16 + g * 4;
#pragma unroll
      for (int r = 0; r < 4; ++r)
        out[(size_t)(mrow + r) * 1024 + n] = acc[i][j][r] + bv;
    }
  }
}

// ---------------------------------------------------------------------------
// MFMA causal flash attention (unchanged from R6).
// ---------------------------------------------------------------------------
__global__ __launch_bounds__(256) void attn_mfma(
    const unsigned short* __restrict__ qh, const unsigned short* __restrict__ kh,
    const unsigned short* __restrict__ vT, unsigned short* __restrict__ Ob) {
  __shared__ __align__(16) unsigned short Klds[2][64 * 64];
  __shared__ __align__(16) unsigned short Vlds[2][64 * 64];

  const int tid = threadIdx.x;
  const int lane = tid & 63;
  const int w = tid >> 6;
  const int bh = blockIdx.y;
  const int b = bh >> 4, h = bh & 15;
  const int q32 = lane & 31;
  const int hi = lane >> 5;

  const char* kbase = (const char*)(kh + (size_t)bh * 2048 * 64);
  const char* vbase = (const char*)(vT + (size_t)bh * 64 * 2048);

  const int lrow = lane >> 3;
  const int cb = (((lane & 7) ^ lrow) << 4);

  auto stage = [&](int buf, int t) {
    const int kv0 = t * 64;
#pragma unroll
    for (int j = 0; j < 2; ++j) {
      const int c = w * 2 + j;
      const int r = c * 8 + lrow;
      gload_lds16(kbase + (size_t)(kv0 + r) * 128 + cb,
                  (char*)Klds[buf] + c * 1024);
      gload_lds16(vbase + (size_t)r * 4096 + (size_t)kv0 * 2 + cb,
                  (char*)Vlds[buf] + c * 1024);
    }
  };

  for (int pass = 0; pass < 2; ++pass) {
    const int qt = pass == 0 ? (15 - (int)blockIdx.x) : (int)blockIdx.x;
    const int qb = qt * 128 + w * 32;
    const int nt = 2 * qt + 2;

    bf16x8 qf[4];
    {
      const unsigned short* qp = qh + ((size_t)bh * 2048 + qb + q32) * 64;
#pragma unroll
      for (int kk = 0; kk < 4; ++kk)
        qf[kk] = *(const bf16x8*)(qp + kk * 16 + hi * 8);
    }

    f32x16 acc_o[2] = {};
    float m_run = -INFINITY, l_run = 0.f;

    stage(0, 0);
    __syncthreads();

    int cur = 0;
    for (int t = 0; t < nt; ++t) {
      const int kv0 = t * 64;
      if (t + 1 < nt) stage(cur ^ 1, t + 1);

      if (kv0 < qb + 32) {
        const char* Kb = (const char*)Klds[cur];
        const char* Vb = (const char*)Vlds[cur];

        f32x16 sacc[2] = {};
        __builtin_amdgcn_s_setprio(1);
#pragma unroll
        for (int kk = 0; kk < 4; ++kk) {
          bf16x8 kf0 = *(const bf16x8*)(Kb + SWZ((q32) * 128 + kk * 32 + hi * 16));
          bf16x8 kf1 = *(const bf16x8*)(Kb + SWZ((32 + q32) * 128 + kk * 32 + hi * 16));
          sacc[0] = __builtin_amdgcn_mfma_f32_32x32x16_bf16(kf0, qf[kk], sacc[0], 0, 0, 0);
          sacc[1] = __builtin_amdgcn_mfma_f32_32x32x16_bf16(kf1, qf[kk], sacc[1], 0, 0, 0);
        }
        __builtin_amdgcn_s_setprio(0);

        if (kv0 + 64 > qb) {
          const int qa = qb + q32;
#pragma unroll
          for (int mkv = 0; mkv < 2; ++mkv)
#pragma unroll
            for (int r = 0; r < 16; ++r) {
              const int kva = kv0 + mkv * 32 + 4 * hi + (r & 3) + 8 * (r >> 2);
              if (kva > qa) sacc[mkv][r] = -INFINITY;
            }
        }

        float mx = -INFINITY;
#pragma unroll
        for (int mkv = 0; mkv < 2; ++mkv)
#pragma unroll
          for (int r = 0; r < 16; ++r) mx = fmaxf(mx, sacc[mkv][r]);
        mx = fmaxf(mx, __shfl_xor(mx, 32));
        if (!__all(mx <= m_run + 8.f)) {
          const float mnew = fmaxf(m_run, mx);
          const float al = exp2f(m_run - mnew);
          m_run = mnew;
          l_run *= al;
          acc_o[0] = acc_o[0] * al;
          acc_o[1] = acc_o[1] * al;
        }

        float ls = 0.f;
        unsigned W[2][8];
#pragma unroll
        for (int mkv = 0; mkv < 2; ++mkv)
#pragma unroll
          for (int s = 0; s < 8; ++s) {
            const float p0 = exp2f(sacc[mkv][2 * s] - m_run);
            const float p1 = exp2f(sacc[mkv][2 * s + 1] - m_run);
            ls += p0 + p1;
            W[mkv][s] = cvtpk_bf16(p0, p1);
          }
        ls += __shfl_xor(ls, 32);
        l_run += ls;

#pragma unroll
        for (int mkv = 0; mkv < 2; ++mkv) {
          pl32swap(W[mkv][0], W[mkv][2]);
          pl32swap(W[mkv][1], W[mkv][3]);
          pl32swap(W[mkv][4], W[mkv][6]);
          pl32swap(W[mkv][5], W[mkv][7]);
        }

        __builtin_amdgcn_s_setprio(1);
#pragma unroll
        for (int wg = 0; wg < 4; ++wg) {
          union { unsigned u[4]; bf16x8 v; } pk;
          pk.u[0] = W[wg >> 1][(wg & 1) * 4 + 0];
          pk.u[1] = W[wg >> 1][(wg & 1) * 4 + 1];
          pk.u[2] = W[wg >> 1][(wg & 1) * 4 + 2];
          pk.u[3] = W[wg >> 1][(wg & 1) * 4 + 3];
          bf16x8 vf0 = *(const bf16x8*)(Vb + SWZ((q32) * 128 + wg * 32 + hi * 16));
          bf16x8 vf1 = *(const bf16x8*)(Vb + SWZ((32 + q32) * 128 + wg * 32 + hi * 16));
          acc_o[0] = __builtin_amdgcn_mfma_f32_32x32x16_bf16(vf0, pk.v, acc_o[0], 0, 0, 0);
          acc_o[1] = __builtin_amdgcn_mfma_f32_32x32x16_bf16(vf1, pk.v, acc_o[1], 0, 0, 0);
        }
        __builtin_amdgcn_s_setprio(0);
      }

      __syncthreads();
      cur ^= 1;
    }

    {
      const float inv = 1.0f / l_run;
      const int qa = qb + q32;
      unsigned short* op = Ob + ((size_t)b * 2048 + qa) * 1024 + h * 64;
#pragma unroll
      for (int md = 0; md < 2; ++md)
#pragma unroll
        for (int rr = 0; rr < 4; ++rr) {
          uint2 u;
          u.x = cvtpk_bf16(acc_o[md][rr * 4 + 0] * inv, acc_o[md][rr * 4 + 1] * inv);
          u.y = cvtpk_bf16(acc_o[md][rr * 4 + 2] * inv, acc_o[md][rr * 4 + 3] * inv);
          *(uint2*)(op + md * 32 + rr * 8 + hi * 4) = u;
        }
    }
  }
}

extern "C" void kernel_launch(void* const* d_in, const int* in_sizes, int n_in,
                              void* d_out, int out_size, void* d_ws, size_t ws_size,
                              hipStream_t stream) {
  (void)in_sizes; (void)n_in; (void)out_size; (void)ws_size;
  const float* q = (const float*)d_in[0];
  const float* k = (const float*)d_in[1];
  const float* v = (const float*)d_in[2];
  const float* Wq = (const float*)d_in[3];
  const float* bq = (const float*)d_in[4];
  const float* Wk = (const float*)d_in[5];
  const float* bk = (const float*)d_in[6];
  const float* Wv = (const float*)d_in[7];
  const float* bv = (const float*)d_in[8];
  const float* Wo = (const float*)d_in[9];
  const float* bo = (const float*)d_in[10];
  float* out = (float*)d_out;

  const size_t SZ = (size_t)4 * 16 * 2048 * 64;   // 8,388,608 elements
  const size_t WSZ = (size_t)1024 * 1024;         // 1,048,576 elements
  unsigned short* qh = (unsigned short*)d_ws;
  unsigned short* kh = qh + SZ;
  unsigned short* vT = kh + SZ;    // V transposed: [bh][d][t]
  unsigned short* Ob = vT + SZ;    // attention output, [B][T][C] bf16
  unsigned short* Wqb = Ob + SZ;   // bf16 weights (Wq pre-scaled)
  unsigned short* Wkb = Wqb + WSZ;
  unsigned short* Wvb = Wkb + WSZ;
  unsigned short* Wob = Wvb + WSZ;

  dim3 g0(1024, 4), b0(256);
  cvt_w<<<g0, b0, 0, stream>>>(Wq, Wk, Wv, Wo, Wqb, Wkb, Wvb, Wob,
                               0.125f * 1.4426950408889634f);

  dim3 g1(64, 8, 3), b1(256);
  proj_gemm3<<<g1, b1, 0, stream>>>(q, k, v, Wqb, Wkb, Wvb, bq, bk, bv, qh, kh, vT);

  dim3 g2(8, 64), b2(256);
  attn_mfma<<<g2, b2, 0, stream>>>(qh, kh, vT, Ob);

  dim3 g3(64, 8), b3(256);
  out_gemm<<<g3, b3, 0, stream>>>(Ob, Wob, bo, out);
}